// Round 1
// baseline (788.102 us; speedup 1.0000x reference)
//
#include <hip/hip_runtime.h>
#include <math.h>

// ---------- types / helpers ----------
typedef __attribute__((ext_vector_type(4))) float f32x4;
typedef __attribute__((ext_vector_type(8))) short short8;
typedef __attribute__((ext_vector_type(4))) short short4v;

#define LAM_INIT 0.9902528750666895f
#define ONE_M_LI 0.0097471249333105f

static __device__ __forceinline__ float bs2f(short s) {
  union { unsigned u; float f; } c;
  c.u = ((unsigned)(unsigned short)s) << 16;
  return c.f;
}
static __device__ __forceinline__ short f2bs(float f) {
  union { float f; unsigned u; } c; c.f = f;
  unsigned r = c.u + 0x7fffu + ((c.u >> 16) & 1u);   // RNE
  return (short)(r >> 16);
}
static __device__ __forceinline__ void gld16(const void* g, void* l) {
  __builtin_amdgcn_global_load_lds(
      (const __attribute__((address_space(1))) void*)g,
      (__attribute__((address_space(3))) void*)l, 16, 0, 0);
}

// ---------- elementwise cast x -> bf16 ----------
__global__ void cast_x(const float* __restrict__ x, short* __restrict__ xb, int n) {
  int i = (blockIdx.x * 256 + threadIdx.x) * 4;
  if (i < n) {
    float4 v = *(const float4*)(x + i);
    short4v o;
    o[0] = f2bs(v.x); o[1] = f2bs(v.y); o[2] = f2bs(v.z); o[3] = f2bs(v.w);
    *(short4v*)(xb + i) = o;
  }
}

// ---------- transpose-cast W (rows x cols fp32) -> dst[c + dstRowOff][r] bf16 ----------
__global__ void transpose_cast(const float* __restrict__ src, short* __restrict__ dst,
                               int srcCols, int dstRowOff, int dstLd) {
  __shared__ float tile[32][33];
  int c0 = blockIdx.x * 32, r0 = blockIdx.y * 32;
  int tx = threadIdx.x, ty = threadIdx.y;
#pragma unroll
  for (int i = 0; i < 32; i += 8)
    tile[ty + i][tx] = src[(long)(r0 + ty + i) * srcCols + c0 + tx];
  __syncthreads();
#pragma unroll
  for (int i = 0; i < 32; i += 8)
    dst[(long)(dstRowOff + c0 + ty + i) * dstLd + r0 + tx] = f2bs(tile[tx][ty + i]);
}

// ---------- m97-style GEMM: C[M x N] = A[M x K] * Bt[N x K]^T, bf16 in ----------
template<int BF16OUT>
__global__ __launch_bounds__(256)
void gemm_bt(const short* __restrict__ A, const short* __restrict__ Bt,
             void* __restrict__ Cp, int K, int N) {
  __shared__ __align__(16) short As[128 * 32];
  __shared__ __align__(16) short Bs[128 * 32];
  const int tid  = threadIdx.x;
  const int lane = tid & 63;
  const int wave = tid >> 6;
  const long mBase = (long)blockIdx.y * 128;
  const long nBase = (long)blockIdx.x * 128;
  const int wm = (wave >> 1) * 64;
  const int wn = (wave & 1) * 64;

  f32x4 acc[4][4];
#pragma unroll
  for (int i = 0; i < 4; i++)
#pragma unroll
    for (int j = 0; j < 4; j++)
#pragma unroll
      for (int r = 0; r < 4; r++) acc[i][j][r] = 0.f;

  // staging: 512 16B segments; seg s -> row s>>2, k-part (s&3)*8; lds byte = s*16
  const int r0  = tid >> 2;
  const int kp0 = (tid & 3) * 8;
  const short* a0 = A  + (mBase + r0) * K + kp0;
  const short* a1 = A  + (mBase + r0 + 64) * K + kp0;
  const short* b0 = Bt + (nBase + r0) * K + kp0;
  const short* b1 = Bt + (nBase + r0 + 64) * K + kp0;
  short* AsW = As + wave * 512;   // wave-uniform LDS base (+ lane*16 by HW)
  short* BsW = Bs + wave * 512;

  const int mr = wm + (lane & 15);
  const int nr = wn + (lane & 15);
  const int kr = (lane >> 4) * 8;

  for (int kt = 0; kt < K; kt += 32) {
    __syncthreads();
    gld16(a0 + kt, AsW);
    gld16(a1 + kt, AsW + 2048);
    gld16(b0 + kt, BsW);
    gld16(b1 + kt, BsW + 2048);
    __syncthreads();
    short8 af[4], bf[4];
#pragma unroll
    for (int mt = 0; mt < 4; mt++) af[mt] = *(const short8*)&As[(mr + mt * 16) * 32 + kr];
#pragma unroll
    for (int nt = 0; nt < 4; nt++) bf[nt] = *(const short8*)&Bs[(nr + nt * 16) * 32 + kr];
#pragma unroll
    for (int mt = 0; mt < 4; mt++)
#pragma unroll
      for (int nt = 0; nt < 4; nt++)
        acc[mt][nt] = __builtin_amdgcn_mfma_f32_16x16x32_bf16(af[mt], bf[nt], acc[mt][nt], 0, 0, 0);
  }

  const long col0 = nBase + wn + (lane & 15);
  const long row0 = mBase + wm + (lane >> 4) * 4;
#pragma unroll
  for (int mt = 0; mt < 4; mt++)
#pragma unroll
    for (int nt = 0; nt < 4; nt++)
#pragma unroll
      for (int rg = 0; rg < 4; rg++) {
        long idx = (row0 + mt * 16 + rg) * N + col0 + nt * 16;
        if (BF16OUT) ((short*)Cp)[idx] = f2bs(acc[mt][nt][rg]);
        else         ((float*)Cp)[idx] = acc[mt][nt][rg];
      }
}

// ---------- fused differential flash attention ----------
// QKV: 4096 x 4096 bf16 rows r = b*2048 + t; cols: q h32*64+d | 2048 + h16*64+d | 3072 + h8*128+dv
// grid (32 qblocks, 16 heads, 2 batch), 256 threads (4 waves x 16 q-rows)
__global__ __launch_bounds__(256)
void diffattn(const short* __restrict__ QKV,
              const float* __restrict__ cosp, const float* __restrict__ sinp,
              const float* __restrict__ lq1, const float* __restrict__ lk1,
              const float* __restrict__ lq2, const float* __restrict__ lk2,
              const float* __restrict__ g,
              short* __restrict__ attnp) {
  __shared__ __align__(16) short Ks[64][72];       // s x d   (roped K, bt-pattern)
  __shared__ __align__(16) short Vs[128][72];      // dv x s  (transposed V, bt-pattern)
  __shared__ __align__(16) short Ps[4][2][16][72]; // per-wave P, A-operand source
  __shared__ float lamsh;

  const int tid  = threadIdx.x;
  const int lane = tid & 63;
  const int wave = tid >> 6;
  const int quad = lane >> 4;
  const int l15  = lane & 15;
  const int qb   = 31 - (int)blockIdx.x;  // heaviest blocks first
  const int h    = blockIdx.y;
  const int b    = blockIdx.z;
  const long rowBase = (long)b * 2048;

  if (tid < 64) {  // lambda = exp(lq1.lk1) - exp(lq2.lk2) + LAM_INIT
    float v1 = lq1[lane] * lk1[lane];
    float v2 = lq2[lane] * lk2[lane];
#pragma unroll
    for (int m = 32; m >= 1; m >>= 1) { v1 += __shfl_xor(v1, m); v2 += __shfl_xor(v2, m); }
    if (lane == 0) lamsh = __expf(v1) - __expf(v2) + LAM_INIT;
  }

  // Q fragments with rope+scale, heads 2h and 2h+1 (A-operand layout)
  short8 qf[2][2];
  {
    const int tq = qb * 64 + wave * 16 + l15;
#pragma unroll
    for (int hd = 0; hd < 2; hd++) {
      const short* qrow = QKV + (rowBase + tq) * 4096 + (2 * h + hd) * 64;
#pragma unroll
      for (int ks = 0; ks < 2; ks++) {
        int d0 = ks * 32 + quad * 8;
        short8 raw = *(const short8*)(qrow + d0);
        short8 ov;
#pragma unroll
        for (int p = 0; p < 4; p++) {
          float x0 = bs2f(raw[2 * p]), x1 = bs2f(raw[2 * p + 1]);
          float c = cosp[tq * 32 + (d0 >> 1) + p];
          float s = sinp[tq * 32 + (d0 >> 1) + p];
          ov[2 * p]     = f2bs((x0 * c - x1 * s) * 0.125f);
          ov[2 * p + 1] = f2bs((x0 * s + x1 * c) * 0.125f);
        }
        qf[hd][ks] = ov;
      }
    }
  }

  float mS[2][4], lS[2][4];
  f32x4 oA[2][8];
#pragma unroll
  for (int hd = 0; hd < 2; hd++) {
#pragma unroll
    for (int r = 0; r < 4; r++) { mS[hd][r] = -INFINITY; lS[hd][r] = 0.f; }
#pragma unroll
    for (int ot = 0; ot < 8; ot++)
#pragma unroll
      for (int r = 0; r < 4; r++) oA[hd][ot][r] = 0.f;
  }

  const int nT = qb + 1;
  for (int st = 0; st < nT; st++) {
    __syncthreads();
    { // stage K tile with rope: thread -> (row i = tid>>2, 16 d at (tid&3)*16)
      const int i = tid >> 2;
      const int dp = (tid & 3) * 16;
      const int s = st * 64 + i;
      const short* kr = QKV + (rowBase + s) * 4096 + 2048 + h * 64 + dp;
      short8 q0 = *(const short8*)kr;
      short8 q1 = *(const short8*)(kr + 8);
      const float* cc = cosp + s * 32 + (dp >> 1);
      const float* ss = sinp + s * 32 + (dp >> 1);
      short8 w0, w1;
#pragma unroll
      for (int p = 0; p < 4; p++) {
        float x0 = bs2f(q0[2 * p]), x1 = bs2f(q0[2 * p + 1]);
        w0[2 * p]     = f2bs(x0 * cc[p] - x1 * ss[p]);
        w0[2 * p + 1] = f2bs(x0 * ss[p] + x1 * cc[p]);
        float y0 = bs2f(q1[2 * p]), y1 = bs2f(q1[2 * p + 1]);
        w1[2 * p]     = f2bs(y0 * cc[4 + p] - y1 * ss[4 + p]);
        w1[2 * p + 1] = f2bs(y0 * ss[4 + p] + y1 * cc[4 + p]);
      }
      *(short8*)&Ks[i][dp] = w0;
      *(short8*)&Ks[i][dp + 8] = w1;
    }
    { // stage V transposed: thread -> (s row tid&63, 32 dv at (tid>>6)*32)
      const int i = tid & 63;
      const int dvb = (tid >> 6) * 32;
      const short* vr = QKV + (rowBase + st * 64 + i) * 4096 + 3072 + (h >> 1) * 128 + dvb;
#pragma unroll
      for (int j = 0; j < 4; j++) {
        short8 rr = *(const short8*)(vr + j * 8);
#pragma unroll
        for (int e = 0; e < 8; e++) Vs[dvb + j * 8 + e][i] = rr[e];
      }
    }
    __syncthreads();

    // S = Q K^T (both heads), C-layout: col s = l15, row q = quad*4+reg
    short8 kf[2][4];
#pragma unroll
    for (int ks = 0; ks < 2; ks++)
#pragma unroll
      for (int nt = 0; nt < 4; nt++)
        kf[ks][nt] = *(const short8*)&Ks[nt * 16 + l15][ks * 32 + quad * 8];
    f32x4 sc[2][4];
#pragma unroll
    for (int hd = 0; hd < 2; hd++)
#pragma unroll
      for (int nt = 0; nt < 4; nt++) {
#pragma unroll
        for (int r = 0; r < 4; r++) sc[hd][nt][r] = 0.f;
#pragma unroll
        for (int ks = 0; ks < 2; ks++)
          sc[hd][nt] = __builtin_amdgcn_mfma_f32_16x16x32_bf16(qf[hd][ks], kf[ks][nt], sc[hd][nt], 0, 0, 0);
      }

    const bool diag = (st == qb);
#pragma unroll
    for (int hd = 0; hd < 2; hd++) {
      if (diag) {
        const int tg = qb * 64 + wave * 16 + quad * 4;
#pragma unroll
        for (int nt = 0; nt < 4; nt++) {
          const int sg = st * 64 + nt * 16 + l15;
#pragma unroll
          for (int r = 0; r < 4; r++)
            if (sg > tg + r) sc[hd][nt][r] = -1e30f;
        }
      }
      float mx[4], al[4];
#pragma unroll
      for (int r = 0; r < 4; r++) {
        float v = fmaxf(fmaxf(sc[hd][0][r], sc[hd][1][r]), fmaxf(sc[hd][2][r], sc[hd][3][r]));
        v = fmaxf(v, __shfl_xor(v, 1));
        v = fmaxf(v, __shfl_xor(v, 2));
        v = fmaxf(v, __shfl_xor(v, 4));
        v = fmaxf(v, __shfl_xor(v, 8));
        mx[r] = v;
      }
#pragma unroll
      for (int r = 0; r < 4; r++) {
        float mn = fmaxf(mS[hd][r], mx[r]);
        al[r] = __expf(mS[hd][r] - mn);
        mS[hd][r] = mn;
      }
      float rs[4] = {0.f, 0.f, 0.f, 0.f};
#pragma unroll
      for (int nt = 0; nt < 4; nt++)
#pragma unroll
        for (int r = 0; r < 4; r++) {
          float p = __expf(sc[hd][nt][r] - mS[hd][r]);
          rs[r] += p;
          Ps[wave][hd][quad * 4 + r][nt * 16 + l15] = f2bs(p);
        }
#pragma unroll
      for (int r = 0; r < 4; r++) {
        float t = rs[r];
        t += __shfl_xor(t, 1); t += __shfl_xor(t, 2);
        t += __shfl_xor(t, 4); t += __shfl_xor(t, 8);
        lS[hd][r] = lS[hd][r] * al[r] + t;
      }
#pragma unroll
      for (int ot = 0; ot < 8; ot++)
#pragma unroll
        for (int r = 0; r < 4; r++) oA[hd][ot][r] *= al[r];
    }

    // PV: P(16 x 64) from LDS as A-frags, V^T rows as B-frags
#pragma unroll
    for (int ks = 0; ks < 2; ks++) {
      short8 p0 = *(const short8*)&Ps[wave][0][l15][ks * 32 + quad * 8];
      short8 p1 = *(const short8*)&Ps[wave][1][l15][ks * 32 + quad * 8];
#pragma unroll
      for (int ot = 0; ot < 8; ot++) {
        short8 vf = *(const short8*)&Vs[ot * 16 + l15][ks * 32 + quad * 8];
        oA[0][ot] = __builtin_amdgcn_mfma_f32_16x16x32_bf16(p0, vf, oA[0][ot], 0, 0, 0);
        oA[1][ot] = __builtin_amdgcn_mfma_f32_16x16x32_bf16(p1, vf, oA[1][ot], 0, 0, 0);
      }
    }
  }

  // epilogue: diff, RMS-norm over 128, * g * (1-LAM_INIT)
  const float lam = lamsh;
  float i1[4], i2[4], ssq[4];
#pragma unroll
  for (int r = 0; r < 4; r++) { i1[r] = 1.f / lS[0][r]; i2[r] = lam / lS[1][r]; ssq[r] = 0.f; }
#pragma unroll
  for (int ot = 0; ot < 8; ot++)
#pragma unroll
    for (int r = 0; r < 4; r++) {
      float d = oA[0][ot][r] * i1[r] - oA[1][ot][r] * i2[r];
      oA[0][ot][r] = d;
      ssq[r] += d * d;
    }
#pragma unroll
  for (int r = 0; r < 4; r++) {
    float t = ssq[r];
    t += __shfl_xor(t, 1); t += __shfl_xor(t, 2);
    t += __shfl_xor(t, 4); t += __shfl_xor(t, 8);
    ssq[r] = ONE_M_LI / sqrtf(t * (1.f / 128.f) + 1e-5f);
  }
  const int tq0 = qb * 64 + wave * 16 + quad * 4;
#pragma unroll
  for (int ot = 0; ot < 8; ot++) {
    const float gv = g[ot * 16 + l15];
#pragma unroll
    for (int r = 0; r < 4; r++)
      attnp[(rowBase + tq0 + r) * 2048 + h * 128 + ot * 16 + l15] = f2bs(oA[0][ot][r] * ssq[r] * gv);
  }
}

// ---------- launch ----------
extern "C" void kernel_launch(void* const* d_in, const int* in_sizes, int n_in,
                              void* d_out, int out_size, void* d_ws, size_t ws_size,
                              hipStream_t stream) {
  const float* x    = (const float*)d_in[0];
  const float* cosp = (const float*)d_in[1];
  const float* sinp = (const float*)d_in[2];
  const float* Wq   = (const float*)d_in[3];
  const float* Wk   = (const float*)d_in[4];
  const float* Wv   = (const float*)d_in[5];
  const float* Wo   = (const float*)d_in[6];
  const float* lq1  = (const float*)d_in[7];
  const float* lk1  = (const float*)d_in[8];
  const float* lq2  = (const float*)d_in[9];
  const float* lk2  = (const float*)d_in[10];
  const float* g    = (const float*)d_in[11];
  float* out = (float*)d_out;

  const size_t MB = 1u << 20;
  char* ws = (char*)d_ws;
  short* xb    = (short*)(ws);            // 16 MB  x bf16 (4096x2048)
  short* Wqkvt = (short*)(ws + 16 * MB);  // 16 MB  [Wq|Wk|Wv]^T bf16 (4096x2048)
  short* Wot   = (short*)(ws + 32 * MB);  //  8 MB  Wo^T bf16 (2048x2048)
  short* QKVb  = (short*)(ws + 40 * MB);  // 32 MB  QKV bf16 (4096x4096)
  short* attnp = (short*)(ws + 72 * MB);  // 16 MB  pre-Wo activations bf16 (4096x2048)

  cast_x<<<8192, 256, 0, stream>>>(x, xb, 8388608);
  dim3 tb(32, 8);
  transpose_cast<<<dim3(64, 64), tb, 0, stream>>>(Wq, Wqkvt, 2048, 0, 2048);
  transpose_cast<<<dim3(32, 64), tb, 0, stream>>>(Wk, Wqkvt, 1024, 2048, 2048);
  transpose_cast<<<dim3(32, 64), tb, 0, stream>>>(Wv, Wqkvt, 1024, 3072, 2048);
  transpose_cast<<<dim3(64, 64), tb, 0, stream>>>(Wo, Wot, 2048, 0, 2048);

  gemm_bt<1><<<dim3(32, 32), 256, 0, stream>>>(xb, Wqkvt, QKVb, 2048, 4096);
  diffattn<<<dim3(32, 16, 2), 256, 0, stream>>>(QKVb, cosp, sinp, lq1, lk1, lq2, lk2, g, attnp);
  gemm_bt<0><<<dim3(16, 32), 256, 0, stream>>>(attnp, Wot, out, 2048, 2048);
}

// Round 2
// 495.754 us; speedup vs baseline: 1.5897x; 1.5897x over previous
//
#include <hip/hip_runtime.h>
#include <math.h>

// ---------- types / helpers ----------
typedef __attribute__((ext_vector_type(4))) float f32x4;
typedef __attribute__((ext_vector_type(8))) short short8;
typedef __attribute__((ext_vector_type(4))) short short4v;

#define LAM_INIT 0.9902528750666895f
#define ONE_M_LI 0.0097471249333105f
#define QSCALE   0.18033688011112042f   // 0.125 * log2(e): S arrives pre-scaled for exp2

static __device__ __forceinline__ float bs2f(short s) {
  union { unsigned u; float f; } c;
  c.u = ((unsigned)(unsigned short)s) << 16;
  return c.f;
}
static __device__ __forceinline__ short f2bs(float f) {
  union { float f; unsigned u; } c; c.f = f;
  unsigned r = c.u + 0x7fffu + ((c.u >> 16) & 1u);   // RNE
  return (short)(r >> 16);
}
static __device__ __forceinline__ void gld16(const void* g, void* l) {
  __builtin_amdgcn_global_load_lds(
      (const __attribute__((address_space(1))) void*)g,
      (__attribute__((address_space(3))) void*)l, 16, 0, 0);
}
#if __has_builtin(__builtin_amdgcn_exp2f)
#define EXP2F(x) __builtin_amdgcn_exp2f(x)
#else
#define EXP2F(x) exp2f(x)
#endif

// ---------- elementwise cast x -> bf16 ----------
__global__ void cast_x(const float* __restrict__ x, short* __restrict__ xb, int n) {
  int i = (blockIdx.x * 256 + threadIdx.x) * 4;
  if (i < n) {
    float4 v = *(const float4*)(x + i);
    short4v o;
    o[0] = f2bs(v.x); o[1] = f2bs(v.y); o[2] = f2bs(v.z); o[3] = f2bs(v.w);
    *(short4v*)(xb + i) = o;
  }
}

// ---------- transpose-cast W (rows x cols fp32) -> dst[c + dstRowOff][r] bf16 ----------
__global__ void transpose_cast(const float* __restrict__ src, short* __restrict__ dst,
                               int srcCols, int dstRowOff, int dstLd) {
  __shared__ float tile[32][33];
  int c0 = blockIdx.x * 32, r0 = blockIdx.y * 32;
  int tx = threadIdx.x, ty = threadIdx.y;
#pragma unroll
  for (int i = 0; i < 32; i += 8)
    tile[ty + i][tx] = src[(long)(r0 + ty + i) * srcCols + c0 + tx];
  __syncthreads();
#pragma unroll
  for (int i = 0; i < 32; i += 8)
    dst[(long)(dstRowOff + c0 + ty + i) * dstLd + r0 + tx] = f2bs(tile[tx][ty + i]);
}

// ---------- m97-style GEMM: C[M x N] = A[M x K] * Bt[N x K]^T, bf16 in ----------
template<int BF16OUT>
__global__ __launch_bounds__(256)
void gemm_bt(const short* __restrict__ A, const short* __restrict__ Bt,
             void* __restrict__ Cp, int K, int N) {
  __shared__ __align__(16) short As[128 * 32];
  __shared__ __align__(16) short Bs[128 * 32];
  const int tid  = threadIdx.x;
  const int lane = tid & 63;
  const int wave = tid >> 6;
  const long mBase = (long)blockIdx.y * 128;
  const long nBase = (long)blockIdx.x * 128;
  const int wm = (wave >> 1) * 64;
  const int wn = (wave & 1) * 64;

  f32x4 acc[4][4];
#pragma unroll
  for (int i = 0; i < 4; i++)
#pragma unroll
    for (int j = 0; j < 4; j++)
#pragma unroll
      for (int r = 0; r < 4; r++) acc[i][j][r] = 0.f;

  const int r0  = tid >> 2;
  const int kp0 = (tid & 3) * 8;
  const short* a0 = A  + (mBase + r0) * K + kp0;
  const short* a1 = A  + (mBase + r0 + 64) * K + kp0;
  const short* b0 = Bt + (nBase + r0) * K + kp0;
  const short* b1 = Bt + (nBase + r0 + 64) * K + kp0;
  short* AsW = As + wave * 512;
  short* BsW = Bs + wave * 512;

  const int mr = wm + (lane & 15);
  const int nr = wn + (lane & 15);
  const int kr = (lane >> 4) * 8;

  for (int kt = 0; kt < K; kt += 32) {
    __syncthreads();
    gld16(a0 + kt, AsW);
    gld16(a1 + kt, AsW + 2048);
    gld16(b0 + kt, BsW);
    gld16(b1 + kt, BsW + 2048);
    __syncthreads();
    short8 af[4], bf[4];
#pragma unroll
    for (int mt = 0; mt < 4; mt++) af[mt] = *(const short8*)&As[(mr + mt * 16) * 32 + kr];
#pragma unroll
    for (int nt = 0; nt < 4; nt++) bf[nt] = *(const short8*)&Bs[(nr + nt * 16) * 32 + kr];
#pragma unroll
    for (int mt = 0; mt < 4; mt++)
#pragma unroll
      for (int nt = 0; nt < 4; nt++)
        acc[mt][nt] = __builtin_amdgcn_mfma_f32_16x16x32_bf16(af[mt], bf[nt], acc[mt][nt], 0, 0, 0);
  }

  const long col0 = nBase + wn + (lane & 15);
  const long row0 = mBase + wm + (lane >> 4) * 4;
#pragma unroll
  for (int mt = 0; mt < 4; mt++)
#pragma unroll
    for (int nt = 0; nt < 4; nt++)
#pragma unroll
      for (int rg = 0; rg < 4; rg++) {
        long idx = (row0 + mt * 16 + rg) * N + col0 + nt * 16;
        if (BF16OUT) ((short*)Cp)[idx] = f2bs(acc[mt][nt][rg]);
        else         ((float*)Cp)[idx] = acc[mt][nt][rg];
      }
}

// ---------- rope Q (scaled by 0.125*log2e) and K in-place on QKVb cols 0..3071 ----------
__global__ __launch_bounds__(256) void rope_qk(short* __restrict__ QKV,
    const float* __restrict__ cosp, const float* __restrict__ sinp) {
  int idx = blockIdx.x * 256 + threadIdx.x;     // 4096 rows * 384 groups
  int r = idx / 384;
  int c8 = idx - r * 384;
  int col = c8 * 8;
  short* p = QKV + (long)r * 4096 + col;
  short8 v = *(const short8*)p;
  int pos = r & 2047;
  int f0 = (col & 63) >> 1;                     // multiple of 4
  float4 c = *(const float4*)(cosp + pos * 32 + f0);
  float4 s = *(const float4*)(sinp + pos * 32 + f0);
  float sc = (col < 2048) ? QSCALE : 1.0f;
  float cc[4] = {c.x, c.y, c.z, c.w};
  float ss[4] = {s.x, s.y, s.z, s.w};
  short8 o;
#pragma unroll
  for (int j = 0; j < 4; j++) {
    float x0 = bs2f(v[2 * j]), x1 = bs2f(v[2 * j + 1]);
    o[2 * j]     = f2bs((x0 * cc[j] - x1 * ss[j]) * sc);
    o[2 * j + 1] = f2bs((x0 * ss[j] + x1 * cc[j]) * sc);
  }
  *(short8*)p = o;
}

// ---------- transpose V part of QKVb -> Vt[b*8+kv][dv 128][t 2048] ----------
__global__ __launch_bounds__(256) void vtrans(const short* __restrict__ QKV,
                                              short* __restrict__ Vt) {
  __shared__ short Ts[64][72];
  const int tid = threadIdx.x;
  const int t0  = blockIdx.x * 64;
  const int dvb = blockIdx.y * 64;
  const int bh  = blockIdx.z;                   // b*8 + kv
  {
    const int tt  = tid >> 2;
    const int c16 = (tid & 3) * 16;
    const short* src = QKV + (long)((bh >> 3) * 2048 + t0 + tt) * 4096 + 3072 + (bh & 7) * 128 + dvb + c16;
    *(short8*)&Ts[tt][c16]     = *(const short8*)src;
    *(short8*)&Ts[tt][c16 + 8] = *(const short8*)(src + 8);
  }
  __syncthreads();
  const int dv = tid >> 2;
  const int tc = (tid & 3) * 16;
  short8 o0, o1;
#pragma unroll
  for (int j = 0; j < 8; j++) { o0[j] = Ts[tc + j][dv]; o1[j] = Ts[tc + 8 + j][dv]; }
  short* dst = Vt + (long)(bh * 128 + dvb + dv) * 2048 + t0 + tc;
  *(short8*)dst       = o0;
  *(short8*)(dst + 8) = o1;
}

// ---------- fused differential flash attention, single-barrier pipelined ----------
// grid (32 qblocks, 16 heads, 2 batch), 256 threads (4 waves x 16 q-rows)
__global__ __launch_bounds__(256)
void diffattn(const short* __restrict__ QKV, const short* __restrict__ Vt,
              const float* __restrict__ lq1, const float* __restrict__ lk1,
              const float* __restrict__ lq2, const float* __restrict__ lk2,
              const float* __restrict__ g, short* __restrict__ attnp) {
  __shared__ __align__(16) short Ks[2][2][64][32];   // [buf][ks][s][8-chunk*4] 16 KB
  __shared__ __align__(16) short Vs[2][2][128][32];  // [buf][ks][dv][..]      32 KB
  __shared__ __align__(16) short Ps[4][16][72];      // per-wave P (q x s)      9 KB
  __shared__ float Lsh[4][2][16];

  const int tid  = threadIdx.x;
  const int lane = tid & 63;
  const int wave = tid >> 6;
  const int quad = lane >> 4;
  const int l15  = lane & 15;
  const int qb   = 31 - (int)blockIdx.x;   // heaviest blocks first
  const int h    = blockIdx.y;
  const int b    = blockIdx.z;
  const long rowBase = (long)b * 2048;

  // lambda in-register (all lanes)
  float lam;
  {
    float v1 = lq1[lane] * lk1[lane];
    float v2 = lq2[lane] * lk2[lane];
#pragma unroll
    for (int m = 32; m >= 1; m >>= 1) { v1 += __shfl_xor(v1, m); v2 += __shfl_xor(v2, m); }
    lam = __expf(v1) - __expf(v2) + LAM_INIT;
  }

  // Q fragments (already roped + scaled), heads 2h, 2h+1
  const int tq = qb * 64 + wave * 16 + l15;
  short8 qf[2][2];
#pragma unroll
  for (int hd = 0; hd < 2; hd++)
#pragma unroll
    for (int ks = 0; ks < 2; ks++)
      qf[hd][ks] = *(const short8*)(QKV + (rowBase + tq) * 4096 + (2 * h + hd) * 64 + ks * 32 + quad * 8);

  // staging bases: thread -> seg (row tid>>2, 16B chunk tid&3)
  const int srow = tid >> 2;
  const int sc16 = (tid & 3) * 8;
  const short* gK = QKV + (rowBase + srow) * 4096 + 2048 + h * 64 + sc16;
  const short* gV = Vt + ((long)(b * 8 + (h >> 1)) * 128 + srow) * 2048 + sc16;
  short* kb0 = &Ks[0][0][0][0] + wave * 512;
  short* vb0 = &Vs[0][0][0][0] + wave * 512;

#define STAGE(ST, BUF) do {                                   \
    const short* gk_ = gK + (long)(ST) * 64 * 4096;           \
    const short* gv_ = gV + (ST) * 64;                        \
    short* kb_ = kb0 + (BUF) * 4096;                          \
    short* vb_ = vb0 + (BUF) * 8192;                          \
    gld16(gk_,      kb_);                                     \
    gld16(gk_ + 32, kb_ + 2048);                              \
    gld16(gv_,               vb_);                            \
    gld16(gv_ + 32,          vb_ + 4096);                     \
    gld16(gv_ + 131072,      vb_ + 2048);                     \
    gld16(gv_ + 131072 + 32, vb_ + 4096 + 2048);              \
  } while (0)

  f32x4 oA[2][8];
  float lS[2][4];
#pragma unroll
  for (int hd = 0; hd < 2; hd++) {
#pragma unroll
    for (int r = 0; r < 4; r++) lS[hd][r] = 0.f;
#pragma unroll
    for (int ot = 0; ot < 8; ot++)
#pragma unroll
      for (int r = 0; r < 4; r++) oA[hd][ot][r] = 0.f;
  }

  STAGE(0, 0);

  for (int st = 0; st <= qb; st++) {
    const int buf = st & 1;
    __syncthreads();                       // publishes buf (drains its gld16s)
    if (st < qb) STAGE(st + 1, buf ^ 1);   // prefetch spans whole compute phase

    short8 kf[2][4];
#pragma unroll
    for (int ks = 0; ks < 2; ks++)
#pragma unroll
      for (int nt = 0; nt < 4; nt++)
        kf[ks][nt] = *(const short8*)&Ks[buf][ks][nt * 16 + l15][quad * 8];

    const bool diag = (st == qb);
    const int tg = qb * 64 + wave * 16 + quad * 4;
#pragma unroll
    for (int hd = 0; hd < 2; hd++) {
      f32x4 sc[4];
#pragma unroll
      for (int nt = 0; nt < 4; nt++) {
#pragma unroll
        for (int r = 0; r < 4; r++) sc[nt][r] = 0.f;
#pragma unroll
        for (int ks = 0; ks < 2; ks++)
          sc[nt] = __builtin_amdgcn_mfma_f32_16x16x32_bf16(qf[hd][ks], kf[ks][nt], sc[nt], 0, 0, 0);
      }
      // p = exp2(S) (no running max: |S| bounded); masked -> 0
#pragma unroll
      for (int nt = 0; nt < 4; nt++) {
        const int sg = st * 64 + nt * 16 + l15;
#pragma unroll
        for (int r = 0; r < 4; r++) {
          float p = EXP2F(sc[nt][r]);
          if (diag && (sg > tg + r)) p = 0.f;
          lS[hd][r] += p;
          Ps[wave][quad * 4 + r][nt * 16 + l15] = f2bs(p);
        }
      }
      // O^T += V^T P^T  (A-frag = V^T rows, B-frag = P rows)
#pragma unroll
      for (int ks = 0; ks < 2; ks++) {
        short8 pf = *(const short8*)&Ps[wave][l15][ks * 32 + quad * 8];
#pragma unroll
        for (int ot = 0; ot < 8; ot++) {
          short8 vf = *(const short8*)&Vs[buf][ks][ot * 16 + l15][quad * 8];
          oA[hd][ot] = __builtin_amdgcn_mfma_f32_16x16x32_bf16(vf, pf, oA[hd][ot], 0, 0, 0);
        }
      }
    }
  }

  // ---- epilogue ----
#pragma unroll
  for (int hd = 0; hd < 2; hd++)
#pragma unroll
    for (int r = 0; r < 4; r++) {
      float t = lS[hd][r];
      t += __shfl_xor(t, 1); t += __shfl_xor(t, 2);
      t += __shfl_xor(t, 4); t += __shfl_xor(t, 8);
      lS[hd][r] = t;
    }
  if (l15 == 0) {
#pragma unroll
    for (int hd = 0; hd < 2; hd++)
#pragma unroll
      for (int r = 0; r < 4; r++) Lsh[wave][hd][quad * 4 + r] = lS[hd][r];
  }
  // same-wave LDS ops are in-order; no barrier needed (per-wave region)
  float i1 = 1.f / Lsh[wave][0][l15];
  float i2 = lam / Lsh[wave][1][l15];
  float ssq = 0.f;
#pragma unroll
  for (int ot = 0; ot < 8; ot++)
#pragma unroll
    for (int r = 0; r < 4; r++) {
      float dd = oA[0][ot][r] * i1 - oA[1][ot][r] * i2;
      oA[0][ot][r] = dd;
      ssq += dd * dd;
    }
  ssq += __shfl_xor(ssq, 16);
  ssq += __shfl_xor(ssq, 32);
  const float scl = ONE_M_LI / sqrtf(ssq * (1.f / 128.f) + 1e-5f);
  const long rowOut = rowBase + tq;
#pragma unroll
  for (int ot = 0; ot < 8; ot++) {
    float4 gv = *(const float4*)(g + ot * 16 + quad * 4);
    short4v o;
    o[0] = f2bs(oA[0][ot][0] * scl * gv.x);
    o[1] = f2bs(oA[0][ot][1] * scl * gv.y);
    o[2] = f2bs(oA[0][ot][2] * scl * gv.z);
    o[3] = f2bs(oA[0][ot][3] * scl * gv.w);
    *(short4v*)(attnp + rowOut * 2048 + h * 128 + ot * 16 + quad * 4) = o;
  }
#undef STAGE
}

// ---------- launch ----------
extern "C" void kernel_launch(void* const* d_in, const int* in_sizes, int n_in,
                              void* d_out, int out_size, void* d_ws, size_t ws_size,
                              hipStream_t stream) {
  const float* x    = (const float*)d_in[0];
  const float* cosp = (const float*)d_in[1];
  const float* sinp = (const float*)d_in[2];
  const float* Wq   = (const float*)d_in[3];
  const float* Wk   = (const float*)d_in[4];
  const float* Wv   = (const float*)d_in[5];
  const float* Wo   = (const float*)d_in[6];
  const float* lq1  = (const float*)d_in[7];
  const float* lk1  = (const float*)d_in[8];
  const float* lq2  = (const float*)d_in[9];
  const float* lk2  = (const float*)d_in[10];
  const float* g    = (const float*)d_in[11];
  float* out = (float*)d_out;

  const size_t MB = 1u << 20;
  char* ws = (char*)d_ws;
  short* xb    = (short*)(ws);            // 16 MB  x bf16 (consumed by GEMM1)
  short* Vt    = (short*)(ws);            //  8 MB  V^T, aliases xb (written after GEMM1)
  short* Wqkvt = (short*)(ws + 16 * MB);  // 16 MB  [Wq|Wk|Wv]^T bf16
  short* Wot   = (short*)(ws + 32 * MB);  //  8 MB  Wo^T bf16
  short* QKVb  = (short*)(ws + 40 * MB);  // 32 MB  QKV bf16 (Q/K roped in-place)
  short* attnp = (short*)(ws + 72 * MB);  // 16 MB  pre-Wo activations bf16

  cast_x<<<8192, 256, 0, stream>>>(x, xb, 8388608);
  dim3 tb(32, 8);
  transpose_cast<<<dim3(64, 64), tb, 0, stream>>>(Wq, Wqkvt, 2048, 0, 2048);
  transpose_cast<<<dim3(32, 64), tb, 0, stream>>>(Wk, Wqkvt, 1024, 2048, 2048);
  transpose_cast<<<dim3(32, 64), tb, 0, stream>>>(Wv, Wqkvt, 1024, 3072, 2048);
  transpose_cast<<<dim3(64, 64), tb, 0, stream>>>(Wo, Wot, 2048, 0, 2048);

  gemm_bt<1><<<dim3(32, 32), 256, 0, stream>>>(xb, Wqkvt, QKVb, 2048, 4096);
  rope_qk<<<6144, 256, 0, stream>>>(QKVb, cosp, sinp);
  vtrans<<<dim3(32, 2, 16), 256, 0, stream>>>(QKVb, Vt);
  diffattn<<<dim3(32, 16, 2), 256, 0, stream>>>(QKVb, Vt, lq1, lk1, lq2, lk2, g, attnp);
  gemm_bt<0><<<dim3(16, 32), 256, 0, stream>>>(attnp, Wot, out, 2048, 2048);
}

// Round 3
// 490.745 us; speedup vs baseline: 1.6059x; 1.0102x over previous
//
#include <hip/hip_runtime.h>
#include <math.h>

// ---------- types / helpers ----------
typedef __attribute__((ext_vector_type(4))) float f32x4;
typedef __attribute__((ext_vector_type(8))) short short8;
typedef __attribute__((ext_vector_type(4))) short short4v;

#define LAM_INIT 0.9902528750666895f
#define ONE_M_LI 0.0097471249333105f
#define QSCALE   0.18033688011112042f   // 0.125 * log2(e): S arrives pre-scaled for exp2

static __device__ __forceinline__ float bs2f(short s) {
  union { unsigned u; float f; } c;
  c.u = ((unsigned)(unsigned short)s) << 16;
  return c.f;
}
static __device__ __forceinline__ short f2bs(float f) {
  union { float f; unsigned u; } c; c.f = f;
  unsigned r = c.u + 0x7fffu + ((c.u >> 16) & 1u);   // RNE
  return (short)(r >> 16);
}
static __device__ __forceinline__ void gld16(const void* g, void* l) {
  __builtin_amdgcn_global_load_lds(
      (const __attribute__((address_space(1))) void*)g,
      (__attribute__((address_space(3))) void*)l, 16, 0, 0);
}
#if __has_builtin(__builtin_amdgcn_exp2f)
#define EXP2F(x) __builtin_amdgcn_exp2f(x)
#else
#define EXP2F(x) exp2f(x)
#endif

// ---------- elementwise cast x -> bf16 ----------
__global__ void cast_x(const float* __restrict__ x, short* __restrict__ xb, int n) {
  int i = (blockIdx.x * 256 + threadIdx.x) * 4;
  if (i < n) {
    float4 v = *(const float4*)(x + i);
    short4v o;
    o[0] = f2bs(v.x); o[1] = f2bs(v.y); o[2] = f2bs(v.z); o[3] = f2bs(v.w);
    *(short4v*)(xb + i) = o;
  }
}

// ---------- transpose-cast W (rows x cols fp32) -> dst[c + dstRowOff][r] bf16 ----------
__global__ void transpose_cast(const float* __restrict__ src, short* __restrict__ dst,
                               int srcCols, int dstRowOff, int dstLd) {
  __shared__ float tile[32][33];
  int c0 = blockIdx.x * 32, r0 = blockIdx.y * 32;
  int tx = threadIdx.x, ty = threadIdx.y;
#pragma unroll
  for (int i = 0; i < 32; i += 8)
    tile[ty + i][tx] = src[(long)(r0 + ty + i) * srcCols + c0 + tx];
  __syncthreads();
#pragma unroll
  for (int i = 0; i < 32; i += 8)
    dst[(long)(dstRowOff + c0 + ty + i) * dstLd + r0 + tx] = f2bs(tile[tx][ty + i]);
}

// ---------- m97-style GEMM: C[M x N] = A[M x K] * Bt[N x K]^T, bf16 in ----------
template<int BF16OUT>
__global__ __launch_bounds__(256)
void gemm_bt(const short* __restrict__ A, const short* __restrict__ Bt,
             void* __restrict__ Cp, int K, int N) {
  __shared__ __align__(16) short As[128 * 32];
  __shared__ __align__(16) short Bs[128 * 32];
  const int tid  = threadIdx.x;
  const int lane = tid & 63;
  const int wave = tid >> 6;
  const long mBase = (long)blockIdx.y * 128;
  const long nBase = (long)blockIdx.x * 128;
  const int wm = (wave >> 1) * 64;
  const int wn = (wave & 1) * 64;

  f32x4 acc[4][4];
#pragma unroll
  for (int i = 0; i < 4; i++)
#pragma unroll
    for (int j = 0; j < 4; j++)
#pragma unroll
      for (int r = 0; r < 4; r++) acc[i][j][r] = 0.f;

  const int r0  = tid >> 2;
  const int kp0 = (tid & 3) * 8;
  const short* a0 = A  + (mBase + r0) * K + kp0;
  const short* a1 = A  + (mBase + r0 + 64) * K + kp0;
  const short* b0 = Bt + (nBase + r0) * K + kp0;
  const short* b1 = Bt + (nBase + r0 + 64) * K + kp0;
  short* AsW = As + wave * 512;
  short* BsW = Bs + wave * 512;

  const int mr = wm + (lane & 15);
  const int nr = wn + (lane & 15);
  const int kr = (lane >> 4) * 8;

  for (int kt = 0; kt < K; kt += 32) {
    __syncthreads();
    gld16(a0 + kt, AsW);
    gld16(a1 + kt, AsW + 2048);
    gld16(b0 + kt, BsW);
    gld16(b1 + kt, BsW + 2048);
    __syncthreads();
    short8 af[4], bf[4];
#pragma unroll
    for (int mt = 0; mt < 4; mt++) af[mt] = *(const short8*)&As[(mr + mt * 16) * 32 + kr];
#pragma unroll
    for (int nt = 0; nt < 4; nt++) bf[nt] = *(const short8*)&Bs[(nr + nt * 16) * 32 + kr];
#pragma unroll
    for (int mt = 0; mt < 4; mt++)
#pragma unroll
      for (int nt = 0; nt < 4; nt++)
        acc[mt][nt] = __builtin_amdgcn_mfma_f32_16x16x32_bf16(af[mt], bf[nt], acc[mt][nt], 0, 0, 0);
  }

  const long col0 = nBase + wn + (lane & 15);
  const long row0 = mBase + wm + (lane >> 4) * 4;
#pragma unroll
  for (int mt = 0; mt < 4; mt++)
#pragma unroll
    for (int nt = 0; nt < 4; nt++)
#pragma unroll
      for (int rg = 0; rg < 4; rg++) {
        long idx = (row0 + mt * 16 + rg) * N + col0 + nt * 16;
        if (BF16OUT) ((short*)Cp)[idx] = f2bs(acc[mt][nt][rg]);
        else         ((float*)Cp)[idx] = acc[mt][nt][rg];
      }
}

// ---------- rope Q in place (scaled by 0.125*log2e), cols 0..2047 of QKVb ----------
__global__ __launch_bounds__(256) void rope_q(short* __restrict__ QKV,
    const float* __restrict__ cosp, const float* __restrict__ sinp) {
  int idx = blockIdx.x * 256 + threadIdx.x;   // 4096 rows * 256 short8-groups
  int r = idx >> 8;
  int col = (idx & 255) * 8;
  short* p = QKV + (long)r * 4096 + col;
  short8 v = *(const short8*)p;
  int pos = r & 2047;
  int f0 = (col & 63) >> 1;
  float4 c = *(const float4*)(cosp + pos * 32 + f0);
  float4 s = *(const float4*)(sinp + pos * 32 + f0);
  float cc[4] = {c.x, c.y, c.z, c.w};
  float ss[4] = {s.x, s.y, s.z, s.w};
  short8 o;
#pragma unroll
  for (int j = 0; j < 4; j++) {
    float x0 = bs2f(v[2 * j]), x1 = bs2f(v[2 * j + 1]);
    o[2 * j]     = f2bs((x0 * cc[j] - x1 * ss[j]) * QSCALE);
    o[2 * j + 1] = f2bs((x0 * ss[j] + x1 * cc[j]) * QSCALE);
  }
  *(short8*)p = o;
}

// ---------- repack K: rope + tile into fragment order ----------
// Kt tile (b,h,stile): idx = (((g*2+ks)*4+c)*16+r)*8+j  <->  K[t=stile*64+g*16+r][d=ks*32+c*8+j]
__global__ __launch_bounds__(256) void repack_k(const short* __restrict__ QKV,
    const float* __restrict__ cosp, const float* __restrict__ sinp,
    short* __restrict__ Kt) {
  const int stile = blockIdx.x, h = blockIdx.y, b = blockIdx.z;
  short* dst = Kt + (long)((b * 16 + h) * 32 + stile) * 4096;
#pragma unroll
  for (int half = 0; half < 2; half++) {
    int o8 = threadIdx.x + half * 256;
    int r = o8 & 15, c = (o8 >> 4) & 3, ks = (o8 >> 6) & 1, gq = o8 >> 7;
    int t = stile * 64 + gq * 16 + r;
    const short* src = QKV + ((long)(b * 2048 + t)) * 4096 + 2048 + h * 64 + ks * 32 + c * 8;
    short8 v = *(const short8*)src;
    const float* cp = cosp + t * 32 + ks * 16 + c * 4;
    const float* sp = sinp + t * 32 + ks * 16 + c * 4;
    short8 o;
#pragma unroll
    for (int j = 0; j < 4; j++) {
      float x0 = bs2f(v[2 * j]), x1 = bs2f(v[2 * j + 1]);
      o[2 * j]     = f2bs(x0 * cp[j] - x1 * sp[j]);
      o[2 * j + 1] = f2bs(x0 * sp[j] + x1 * cp[j]);
    }
    *(short8*)(dst + o8 * 8) = o;
  }
}

// ---------- repack V: transpose + tile into fragment order ----------
// Vt tile (b,kv,stile): idx = (((g*2+ks)*4+c)*16+r)*8+j <-> V^T[dv=g*16+r][t=stile*64+ks*32+c*8+j]
__global__ __launch_bounds__(256) void repack_v(const short* __restrict__ QKV,
                                                short* __restrict__ Vt) {
  __shared__ short Ts[64][130];
  const int tid = threadIdx.x;
  const int stile = blockIdx.x, kv = blockIdx.y, b = blockIdx.z;
#pragma unroll
  for (int half = 0; half < 2; half++) {
    int trow = half * 32 + (tid >> 3);
    int hwc = (tid & 7) * 16;
    const short* src = QKV + ((long)(b * 2048 + stile * 64 + trow)) * 4096 + 3072 + kv * 128 + hwc;
    *(short8*)&Ts[trow][hwc]     = *(const short8*)src;
    *(short8*)&Ts[trow][hwc + 8] = *(const short8*)(src + 8);
  }
  __syncthreads();
  short* dst = Vt + (long)((b * 8 + kv) * 32 + stile) * 8192;
#pragma unroll
  for (int k4 = 0; k4 < 4; k4++) {
    int o8 = tid + k4 * 256;
    int r = o8 & 15, c = (o8 >> 4) & 3, ks = (o8 >> 6) & 1, gq = o8 >> 7;
    int tt = ks * 32 + c * 8;
    int dv = gq * 16 + r;
    short8 o;
#pragma unroll
    for (int j = 0; j < 8; j++) o[j] = Ts[tt + j][dv];
    *(short8*)(dst + o8 * 8) = o;
  }
}

// ---------- fused differential flash attention: barrier-free, direct-load fragments ----------
// grid (16 h, 2 b, 32 z->qb), 256 threads (4 independent waves x 16 q-rows)
__global__ __launch_bounds__(256, 3)
void diffattn(const short* __restrict__ QKV, const short* __restrict__ Kt,
              const short* __restrict__ Vt,
              const float* __restrict__ lq1, const float* __restrict__ lk1,
              const float* __restrict__ lq2, const float* __restrict__ lk2,
              const float* __restrict__ g, short* __restrict__ attnp) {
  __shared__ __align__(16) short Ps[4][2][16][72];   // per-wave P, both heads (18.4 KB)

  const int tid  = threadIdx.x;
  const int lane = tid & 63;
  const int wave = tid >> 6;
  const int quad = lane >> 4;
  const int l15  = lane & 15;
  const int h    = blockIdx.x;
  const int b    = blockIdx.y;
  const int qb   = 31 - (int)blockIdx.z;   // heavy blocks dispatched first
  const long rowBase = (long)b * 2048;

  // lambda (all lanes)
  float lam;
  {
    float v1 = lq1[lane] * lk1[lane];
    float v2 = lq2[lane] * lk2[lane];
#pragma unroll
    for (int m = 32; m >= 1; m >>= 1) { v1 += __shfl_xor(v1, m); v2 += __shfl_xor(v2, m); }
    lam = __expf(v1) - __expf(v2) + LAM_INIT;
  }

  // Q fragments (roped + scaled), heads 2h, 2h+1 (A-operand layout)
  const int tq = qb * 64 + wave * 16 + l15;
  short8 qf[2][2];
#pragma unroll
  for (int hd = 0; hd < 2; hd++)
#pragma unroll
    for (int ks = 0; ks < 2; ks++)
      qf[hd][ks] = *(const short8*)(QKV + (rowBase + tq) * 4096 + (2 * h + hd) * 64 + ks * 32 + quad * 8);

  const short* KtB = Kt + (long)((b * 16 + h) * 32) * 4096;
  const short* VtB = Vt + (long)((b * 8 + (h >> 1)) * 32) * 8192;
  const int fo = (quad * 16 + l15) * 8;   // lane offset inside a fragment group

  float lS[2][4];
  f32x4 oA[2][8];
#pragma unroll
  for (int hd = 0; hd < 2; hd++) {
#pragma unroll
    for (int r = 0; r < 4; r++) lS[hd][r] = 0.f;
#pragma unroll
    for (int ot = 0; ot < 8; ot++)
#pragma unroll
      for (int r = 0; r < 4; r++) oA[hd][ot][r] = 0.f;
  }

  for (int st = 0; st <= qb; st++) {
    const short* Ktile = KtB + st * 4096;
    const short* Vtile = VtB + (long)st * 8192;

    // S = Q K^T, both heads; C-layout (row q = quad*4+r, col s = nt*16+l15)
    f32x4 sc[2][4];
#pragma unroll
    for (int hd = 0; hd < 2; hd++)
#pragma unroll
      for (int nt = 0; nt < 4; nt++)
#pragma unroll
        for (int r = 0; r < 4; r++) sc[hd][nt][r] = 0.f;
#pragma unroll
    for (int ks = 0; ks < 2; ks++) {
      short8 kf[4];
#pragma unroll
      for (int nt = 0; nt < 4; nt++)
        kf[nt] = *(const short8*)(Ktile + (nt * 2 + ks) * 512 + fo);
#pragma unroll
      for (int nt = 0; nt < 4; nt++) {
        sc[0][nt] = __builtin_amdgcn_mfma_f32_16x16x32_bf16(qf[0][ks], kf[nt], sc[0][nt], 0, 0, 0);
        sc[1][nt] = __builtin_amdgcn_mfma_f32_16x16x32_bf16(qf[1][ks], kf[nt], sc[1][nt], 0, 0, 0);
      }
    }

    // softmax terms: p = exp2(S) (S pre-scaled; bounded, no running max)
    const bool diag = (st == qb);
    const int tg = qb * 64 + wave * 16 + quad * 4;
#pragma unroll
    for (int hd = 0; hd < 2; hd++)
#pragma unroll
      for (int nt = 0; nt < 4; nt++) {
        const int sg = st * 64 + nt * 16 + l15;
#pragma unroll
        for (int r = 0; r < 4; r++) {
          float p = EXP2F(sc[hd][nt][r]);
          if (diag && (sg > tg + r)) p = 0.f;
          lS[hd][r] += p;
          Ps[wave][hd][quad * 4 + r][nt * 16 + l15] = f2bs(p);
        }
      }

    // O += P V  (A = P rows, B = V^T rows; vf shared across both heads)
#pragma unroll
    for (int ks = 0; ks < 2; ks++) {
      short8 p0 = *(const short8*)&Ps[wave][0][l15][ks * 32 + quad * 8];
      short8 p1 = *(const short8*)&Ps[wave][1][l15][ks * 32 + quad * 8];
#pragma unroll
      for (int ot = 0; ot < 8; ot++) {
        short8 vf = *(const short8*)(Vtile + (ot * 2 + ks) * 512 + fo);
        oA[0][ot] = __builtin_amdgcn_mfma_f32_16x16x32_bf16(p0, vf, oA[0][ot], 0, 0, 0);
        oA[1][ot] = __builtin_amdgcn_mfma_f32_16x16x32_bf16(p1, vf, oA[1][ot], 0, 0, 0);
      }
    }
  }

  // ---- epilogue: O rows q = quad*4+r, cols dv = ot*16+l15 ----
#pragma unroll
  for (int hd = 0; hd < 2; hd++)
#pragma unroll
    for (int r = 0; r < 4; r++) {
      float t = lS[hd][r];
      t += __shfl_xor(t, 1); t += __shfl_xor(t, 2);
      t += __shfl_xor(t, 4); t += __shfl_xor(t, 8);
      lS[hd][r] = t;
    }
  float i1[4], i2[4], ssq[4];
#pragma unroll
  for (int r = 0; r < 4; r++) { i1[r] = 1.f / lS[0][r]; i2[r] = lam / lS[1][r]; ssq[r] = 0.f; }
#pragma unroll
  for (int ot = 0; ot < 8; ot++)
#pragma unroll
    for (int r = 0; r < 4; r++) {
      float d = oA[0][ot][r] * i1[r] - oA[1][ot][r] * i2[r];
      oA[0][ot][r] = d;
      ssq[r] += d * d;
    }
#pragma unroll
  for (int r = 0; r < 4; r++) {
    float t = ssq[r];
    t += __shfl_xor(t, 1); t += __shfl_xor(t, 2);
    t += __shfl_xor(t, 4); t += __shfl_xor(t, 8);
    ssq[r] = ONE_M_LI / sqrtf(t * (1.f / 128.f) + 1e-5f);
  }
  const long orow = rowBase + qb * 64 + wave * 16 + quad * 4;
#pragma unroll
  for (int ot = 0; ot < 8; ot++) {
    const float gv = g[ot * 16 + l15];
#pragma unroll
    for (int r = 0; r < 4; r++)
      attnp[(orow + r) * 2048 + h * 128 + ot * 16 + l15] = f2bs(oA[0][ot][r] * ssq[r] * gv);
  }
}

// ---------- launch ----------
extern "C" void kernel_launch(void* const* d_in, const int* in_sizes, int n_in,
                              void* d_out, int out_size, void* d_ws, size_t ws_size,
                              hipStream_t stream) {
  const float* x    = (const float*)d_in[0];
  const float* cosp = (const float*)d_in[1];
  const float* sinp = (const float*)d_in[2];
  const float* Wq   = (const float*)d_in[3];
  const float* Wk   = (const float*)d_in[4];
  const float* Wv   = (const float*)d_in[5];
  const float* Wo   = (const float*)d_in[6];
  const float* lq1  = (const float*)d_in[7];
  const float* lk1  = (const float*)d_in[8];
  const float* lq2  = (const float*)d_in[9];
  const float* lk2  = (const float*)d_in[10];
  const float* g    = (const float*)d_in[11];
  float* out = (float*)d_out;

  const size_t MB = 1u << 20;
  char* ws = (char*)d_ws;
  short* xb    = (short*)(ws);            // 16 MB  x bf16 (consumed by GEMM1)
  short* Kt    = (short*)(ws);            //  8 MB  K tiled (aliases xb, written after GEMM1)
  short* Vt    = (short*)(ws + 8 * MB);   //  8 MB  V^T tiled
  short* Wqkvt = (short*)(ws + 16 * MB);  // 16 MB  [Wq|Wk|Wv]^T bf16
  short* Wot   = (short*)(ws + 32 * MB);  //  8 MB  Wo^T bf16
  short* QKVb  = (short*)(ws + 40 * MB);  // 32 MB  QKV bf16 (Q roped in place)
  short* attnp = (short*)(ws + 72 * MB);  // 16 MB  pre-Wo activations bf16

  cast_x<<<8192, 256, 0, stream>>>(x, xb, 8388608);
  dim3 tb(32, 8);
  transpose_cast<<<dim3(64, 64), tb, 0, stream>>>(Wq, Wqkvt, 2048, 0, 2048);
  transpose_cast<<<dim3(32, 64), tb, 0, stream>>>(Wk, Wqkvt, 1024, 2048, 2048);
  transpose_cast<<<dim3(32, 64), tb, 0, stream>>>(Wv, Wqkvt, 1024, 3072, 2048);
  transpose_cast<<<dim3(64, 64), tb, 0, stream>>>(Wo, Wot, 2048, 0, 2048);

  gemm_bt<1><<<dim3(32, 32), 256, 0, stream>>>(xb, Wqkvt, QKVb, 2048, 4096);
  rope_q<<<4096, 256, 0, stream>>>(QKVb, cosp, sinp);
  repack_k<<<dim3(32, 16, 2), 256, 0, stream>>>(QKVb, cosp, sinp, Kt);
  repack_v<<<dim3(32, 8, 2), 256, 0, stream>>>(QKVb, Vt);
  diffattn<<<dim3(16, 2, 32), 256, 0, stream>>>(QKVb, Kt, Vt, lq1, lk1, lq2, lk2, g, attnp);
  gemm_bt<0><<<dim3(16, 32), 256, 0, stream>>>(attnp, Wot, out, 2048, 2048);
}

// Round 5
// 382.313 us; speedup vs baseline: 2.0614x; 1.2836x over previous
//
#include <hip/hip_runtime.h>
#include <math.h>

// ---------- types / helpers ----------
typedef __attribute__((ext_vector_type(4))) float f32x4;
typedef __attribute__((ext_vector_type(8))) short short8;
typedef __attribute__((ext_vector_type(4))) short short4v;

#define LAM_INIT 0.9902528750666895f
#define ONE_M_LI 0.0097471249333105f
#define QSCALE   0.18033688011112042f   // 0.125 * log2(e): S arrives pre-scaled for exp2

static __device__ __forceinline__ float bs2f(short s) {
  union { unsigned u; float f; } c;
  c.u = ((unsigned)(unsigned short)s) << 16;
  return c.f;
}
static __device__ __forceinline__ short f2bs(float f) {
  union { float f; unsigned u; } c; c.f = f;
  unsigned r = c.u + 0x7fffu + ((c.u >> 16) & 1u);   // RNE
  return (short)(r >> 16);
}
static __device__ __forceinline__ short f2bs_fast(float f) {  // round-half-up (P only)
  union { float f; unsigned u; } c; c.f = f;
  return (short)((c.u + 0x8000u) >> 16);
}
static __device__ __forceinline__ void gld16(const void* g, void* l) {
  __builtin_amdgcn_global_load_lds(
      (const __attribute__((address_space(1))) void*)g,
      (__attribute__((address_space(3))) void*)l, 16, 0, 0);
}
#if __has_builtin(__builtin_amdgcn_exp2f)
#define EXP2F(x) __builtin_amdgcn_exp2f(x)
#else
#define EXP2F(x) exp2f(x)
#endif

// ---------- elementwise cast x -> bf16 ----------
__global__ void cast_x(const float* __restrict__ x, short* __restrict__ xb, int n) {
  int i = (blockIdx.x * 256 + threadIdx.x) * 4;
  if (i < n) {
    float4 v = *(const float4*)(x + i);
    short4v o;
    o[0] = f2bs(v.x); o[1] = f2bs(v.y); o[2] = f2bs(v.z); o[3] = f2bs(v.w);
    *(short4v*)(xb + i) = o;
  }
}

// ---------- transpose-cast W (rows x cols fp32) -> dst[c + dstRowOff][r] bf16 ----------
__global__ void transpose_cast(const float* __restrict__ src, short* __restrict__ dst,
                               int srcCols, int dstRowOff, int dstLd) {
  __shared__ float tile[32][33];
  int c0 = blockIdx.x * 32, r0 = blockIdx.y * 32;
  int tx = threadIdx.x, ty = threadIdx.y;
#pragma unroll
  for (int i = 0; i < 32; i += 8)
    tile[ty + i][tx] = src[(long)(r0 + ty + i) * srcCols + c0 + tx];
  __syncthreads();
#pragma unroll
  for (int i = 0; i < 32; i += 8)
    dst[(long)(dstRowOff + c0 + ty + i) * dstLd + r0 + tx] = f2bs(tile[tx][ty + i]);
}

// ---------- m97-style GEMM: C[M x N] = A[M x K] * Bt[N x K]^T, bf16 in ----------
template<int BF16OUT>
__global__ __launch_bounds__(256)
void gemm_bt(const short* __restrict__ A, const short* __restrict__ Bt,
             void* __restrict__ Cp, int K, int N) {
  __shared__ __align__(16) short As[128 * 32];
  __shared__ __align__(16) short Bs[128 * 32];
  const int tid  = threadIdx.x;
  const int lane = tid & 63;
  const int wave = tid >> 6;
  const long mBase = (long)blockIdx.y * 128;
  const long nBase = (long)blockIdx.x * 128;
  const int wm = (wave >> 1) * 64;
  const int wn = (wave & 1) * 64;

  f32x4 acc[4][4];
#pragma unroll
  for (int i = 0; i < 4; i++)
#pragma unroll
    for (int j = 0; j < 4; j++)
#pragma unroll
      for (int r = 0; r < 4; r++) acc[i][j][r] = 0.f;

  const int r0  = tid >> 2;
  const int kp0 = (tid & 3) * 8;
  const short* a0 = A  + (mBase + r0) * K + kp0;
  const short* a1 = A  + (mBase + r0 + 64) * K + kp0;
  const short* b0 = Bt + (nBase + r0) * K + kp0;
  const short* b1 = Bt + (nBase + r0 + 64) * K + kp0;
  short* AsW = As + wave * 512;
  short* BsW = Bs + wave * 512;

  const int mr = wm + (lane & 15);
  const int nr = wn + (lane & 15);
  const int kr = (lane >> 4) * 8;

  for (int kt = 0; kt < K; kt += 32) {
    __syncthreads();
    gld16(a0 + kt, AsW);
    gld16(a1 + kt, AsW + 2048);
    gld16(b0 + kt, BsW);
    gld16(b1 + kt, BsW + 2048);
    __syncthreads();
    short8 af[4], bf[4];
#pragma unroll
    for (int mt = 0; mt < 4; mt++) af[mt] = *(const short8*)&As[(mr + mt * 16) * 32 + kr];
#pragma unroll
    for (int nt = 0; nt < 4; nt++) bf[nt] = *(const short8*)&Bs[(nr + nt * 16) * 32 + kr];
#pragma unroll
    for (int mt = 0; mt < 4; mt++)
#pragma unroll
      for (int nt = 0; nt < 4; nt++)
        acc[mt][nt] = __builtin_amdgcn_mfma_f32_16x16x32_bf16(af[mt], bf[nt], acc[mt][nt], 0, 0, 0);
  }

  const long col0 = nBase + wn + (lane & 15);
  const long row0 = mBase + wm + (lane >> 4) * 4;
#pragma unroll
  for (int mt = 0; mt < 4; mt++)
#pragma unroll
    for (int nt = 0; nt < 4; nt++)
#pragma unroll
      for (int rg = 0; rg < 4; rg++) {
        long idx = (row0 + mt * 16 + rg) * N + col0 + nt * 16;
        if (BF16OUT) ((short*)Cp)[idx] = f2bs(acc[mt][nt][rg]);
        else         ((float*)Cp)[idx] = acc[mt][nt][rg];
      }
}

// ---------- rope Q in place (scaled by 0.125*log2e), cols 0..2047 of QKVb ----------
__global__ __launch_bounds__(256) void rope_q(short* __restrict__ QKV,
    const float* __restrict__ cosp, const float* __restrict__ sinp) {
  int idx = blockIdx.x * 256 + threadIdx.x;   // 4096 rows * 256 short8-groups
  int r = idx >> 8;
  int col = (idx & 255) * 8;
  short* p = QKV + (long)r * 4096 + col;
  short8 v = *(const short8*)p;
  int pos = r & 2047;
  int f0 = (col & 63) >> 1;
  float4 c = *(const float4*)(cosp + pos * 32 + f0);
  float4 s = *(const float4*)(sinp + pos * 32 + f0);
  float cc[4] = {c.x, c.y, c.z, c.w};
  float ss[4] = {s.x, s.y, s.z, s.w};
  short8 o;
#pragma unroll
  for (int j = 0; j < 4; j++) {
    float x0 = bs2f(v[2 * j]), x1 = bs2f(v[2 * j + 1]);
    o[2 * j]     = f2bs((x0 * cc[j] - x1 * ss[j]) * QSCALE);
    o[2 * j + 1] = f2bs((x0 * ss[j] + x1 * cc[j]) * QSCALE);
  }
  *(short8*)p = o;
}

// ---------- repack K: rope + tile into fragment order ----------
// Kt tile (b,h,stile): idx = (((g*2+ks)*4+c)*16+r)*8+j  <->  K[t=stile*64+g*16+r][d=ks*32+c*8+j]
__global__ __launch_bounds__(256) void repack_k(const short* __restrict__ QKV,
    const float* __restrict__ cosp, const float* __restrict__ sinp,
    short* __restrict__ Kt) {
  const int stile = blockIdx.x, h = blockIdx.y, b = blockIdx.z;
  short* dst = Kt + (long)((b * 16 + h) * 32 + stile) * 4096;
#pragma unroll
  for (int half = 0; half < 2; half++) {
    int o8 = threadIdx.x + half * 256;
    int r = o8 & 15, c = (o8 >> 4) & 3, ks = (o8 >> 6) & 1, gq = o8 >> 7;
    int t = stile * 64 + gq * 16 + r;
    const short* src = QKV + ((long)(b * 2048 + t)) * 4096 + 2048 + h * 64 + ks * 32 + c * 8;
    short8 v = *(const short8*)src;
    const float* cp = cosp + t * 32 + ks * 16 + c * 4;
    const float* sp = sinp + t * 32 + ks * 16 + c * 4;
    short8 o;
#pragma unroll
    for (int j = 0; j < 4; j++) {
      float x0 = bs2f(v[2 * j]), x1 = bs2f(v[2 * j + 1]);
      o[2 * j]     = f2bs(x0 * cp[j] - x1 * sp[j]);
      o[2 * j + 1] = f2bs(x0 * sp[j] + x1 * cp[j]);
    }
    *(short8*)(dst + o8 * 8) = o;
  }
}

// ---------- repack V: transpose + tile into fragment order ----------
// Vt tile (b,kv,stile): idx = (((g*2+ks)*4+c)*16+r)*8+j <-> V^T[dv=g*16+r][t=stile*64+ks*32+c*8+j]
__global__ __launch_bounds__(256) void repack_v(const short* __restrict__ QKV,
                                                short* __restrict__ Vt) {
  __shared__ short Ts[64][130];
  const int tid = threadIdx.x;
  const int stile = blockIdx.x, kv = blockIdx.y, b = blockIdx.z;
#pragma unroll
  for (int half = 0; half < 2; half++) {
    int trow = half * 32 + (tid >> 3);
    int hwc = (tid & 7) * 16;
    const short* src = QKV + ((long)(b * 2048 + stile * 64 + trow)) * 4096 + 3072 + kv * 128 + hwc;
    *(short8*)&Ts[trow][hwc]     = *(const short8*)src;
    *(short8*)&Ts[trow][hwc + 8] = *(const short8*)(src + 8);
  }
  __syncthreads();
  short* dst = Vt + (long)((b * 8 + kv) * 32 + stile) * 8192;
#pragma unroll
  for (int k4 = 0; k4 < 4; k4++) {
    int o8 = tid + k4 * 256;
    int r = o8 & 15, c = (o8 >> 4) & 3, ks = (o8 >> 6) & 1, gq = o8 >> 7;
    int tt = ks * 32 + c * 8;
    int dv = gq * 16 + r;
    short8 o;
#pragma unroll
    for (int j = 0; j < 8; j++) o[j] = Ts[tt + j][dv];
    *(short8*)(dst + o8 * 8) = o;
  }
}

// ---------- fused differential flash attention ----------
// LDS-staged fragment tiles (conflict-free b128 reads), double-buffered, 1 barrier/iter,
// XCD-local flat grid: bx&7 -> XCD, 4 (h,b) sets per XCD (2MB K/V working set < 4MB L2).
// 1024 blocks, 256 threads (4 waves x 16 q-rows).
__global__ __launch_bounds__(256, 2)
void diffattn(const short* __restrict__ QKV, const short* __restrict__ Kt,
              const short* __restrict__ Vt,
              const float* __restrict__ lq1, const float* __restrict__ lk1,
              const float* __restrict__ lq2, const float* __restrict__ lk2,
              const float* __restrict__ g, short* __restrict__ attnp) {
  __shared__ __align__(16) short Ks[2][4096];        // 16 KB  K tile (fragment order)
  __shared__ __align__(16) short Vs[2][8192];        // 32 KB  V tile (fragment order)
  __shared__ __align__(16) short Ps[4][2][16][72];   // 18.4 KB per-wave P round-trip

  const int tid  = threadIdx.x;
  const int lane = tid & 63;
  const int wave = tid >> 6;
  const int quad = lane >> 4;
  const int l15  = lane & 15;

  // XCD-local decomposition of flat blockIdx
  const int bx   = blockIdx.x;
  const int xcd  = bx & 7;
  const int slot = bx >> 3;               // 0..127
  const int hb   = xcd * 4 + (slot & 3);  // 0..31
  const int h    = hb & 15;
  const int b    = hb >> 4;
  const int qb   = 31 - (slot >> 2);      // heavy blocks dispatched first
  const long rowBase = (long)b * 2048;

  // lambda (all lanes)
  float lam;
  {
    float v1 = lq1[lane] * lk1[lane];
    float v2 = lq2[lane] * lk2[lane];
#pragma unroll
    for (int m = 32; m >= 1; m >>= 1) { v1 += __shfl_xor(v1, m); v2 += __shfl_xor(v2, m); }
    lam = __expf(v1) - __expf(v2) + LAM_INIT;
  }

  // Q fragments (roped + scaled), heads 2h, 2h+1 (A-operand layout)
  const int tq = qb * 64 + wave * 16 + l15;
  short8 qf[2][2];
#pragma unroll
  for (int hd = 0; hd < 2; hd++)
#pragma unroll
    for (int ks = 0; ks < 2; ks++)
      qf[hd][ks] = *(const short8*)(QKV + (rowBase + tq) * 4096 + (2 * h + hd) * 64 + ks * 32 + quad * 8);

  const short* KtB = Kt + (long)((b * 16 + h) * 32) * 4096;
  const short* VtB = Vt + (long)((b * 8 + (h >> 1)) * 32) * 8192;
  short* KsB = &Ks[0][0];
  short* VsB = &Vs[0][0];

  // staging split: wave w loads K segs {2w,2w+1} + V segs {4w..4w+3}
  // global address is PER-LANE (+lane*8 shorts = 16B); LDS base is wave-uniform (HW adds lane*16B)
#define STAGE(ST, BUF) do {                                                  \
    const short* kg_ = KtB + (long)(ST) * 4096 + wave * 1024 + lane * 8;     \
    const short* vg_ = VtB + (long)(ST) * 8192 + wave * 2048 + lane * 8;     \
    short* kl_ = KsB + (BUF) * 4096 + wave * 1024;                           \
    short* vl_ = VsB + (BUF) * 8192 + wave * 2048;                           \
    gld16(kg_,        kl_);                                                  \
    gld16(kg_ + 512,  kl_ + 512);                                            \
    gld16(vg_,        vl_);                                                  \
    gld16(vg_ + 512,  vl_ + 512);                                            \
    gld16(vg_ + 1024, vl_ + 1024);                                           \
    gld16(vg_ + 1536, vl_ + 1536);                                           \
  } while (0)

  float lS[2][4];
  f32x4 oA[2][8];
#pragma unroll
  for (int hd = 0; hd < 2; hd++) {
#pragma unroll
    for (int r = 0; r < 4; r++) lS[hd][r] = 0.f;
#pragma unroll
    for (int ot = 0; ot < 8; ot++)
#pragma unroll
      for (int r = 0; r < 4; r++) oA[hd][ot][r] = 0.f;
  }

  STAGE(0, 0);

  for (int st = 0; st <= qb; st++) {
    const int buf = st & 1;
    __syncthreads();                      // publishes buf (drains its gld16s)
    if (st < qb) STAGE(st + 1, buf ^ 1);  // prefetch spans the whole compute phase

    const short* Ktile = KsB + buf * 4096;
    const short* Vtile = VsB + buf * 8192;

    // S = Q K^T, both heads; C-layout (row q = quad*4+r, col s = nt*16+l15)
    f32x4 sc[2][4];
#pragma unroll
    for (int hd = 0; hd < 2; hd++)
#pragma unroll
      for (int nt = 0; nt < 4; nt++)
#pragma unroll
        for (int r = 0; r < 4; r++) sc[hd][nt][r] = 0.f;
#pragma unroll
    for (int ks = 0; ks < 2; ks++) {
      short8 kf[4];
#pragma unroll
      for (int nt = 0; nt < 4; nt++)
        kf[nt] = *(const short8*)(Ktile + (nt * 2 + ks) * 512 + lane * 8);
#pragma unroll
      for (int nt = 0; nt < 4; nt++) {
        sc[0][nt] = __builtin_amdgcn_mfma_f32_16x16x32_bf16(qf[0][ks], kf[nt], sc[0][nt], 0, 0, 0);
        sc[1][nt] = __builtin_amdgcn_mfma_f32_16x16x32_bf16(qf[1][ks], kf[nt], sc[1][nt], 0, 0, 0);
      }
    }

    // softmax terms: p = exp2(S) (S pre-scaled; bounded, no running max)
    const bool diag = (st == qb);
    const int tg = qb * 64 + wave * 16 + quad * 4;
#pragma unroll
    for (int hd = 0; hd < 2; hd++)
#pragma unroll
      for (int nt = 0; nt < 4; nt++) {
        const int sg = st * 64 + nt * 16 + l15;
#pragma unroll
        for (int r = 0; r < 4; r++) {
          float p = EXP2F(sc[hd][nt][r]);
          if (diag && (sg > tg + r)) p = 0.f;
          lS[hd][r] += p;
          Ps[wave][hd][quad * 4 + r][nt * 16 + l15] = f2bs_fast(p);
        }
      }

    // O += P V  (A = P rows, B = V^T rows; vf shared across both heads)
#pragma unroll
    for (int ks = 0; ks < 2; ks++) {
      short8 p0 = *(const short8*)&Ps[wave][0][l15][ks * 32 + quad * 8];
      short8 p1 = *(const short8*)&Ps[wave][1][l15][ks * 32 + quad * 8];
#pragma unroll
      for (int ot = 0; ot < 8; ot++) {
        short8 vf = *(const short8*)(Vtile + (ot * 2 + ks) * 512 + lane * 8);
        oA[0][ot] = __builtin_amdgcn_mfma_f32_16x16x32_bf16(p0, vf, oA[0][ot], 0, 0, 0);
        oA[1][ot] = __builtin_amdgcn_mfma_f32_16x16x32_bf16(p1, vf, oA[1][ot], 0, 0, 0);
      }
    }
  }
#undef STAGE

  // ---- epilogue: O rows q = quad*4+r, cols dv = ot*16+l15 ----
#pragma unroll
  for (int hd = 0; hd < 2; hd++)
#pragma unroll
    for (int r = 0; r < 4; r++) {
      float t = lS[hd][r];
      t += __shfl_xor(t, 1); t += __shfl_xor(t, 2);
      t += __shfl_xor(t, 4); t += __shfl_xor(t, 8);
      lS[hd][r] = t;
    }
  float i1[4], i2[4], ssq[4];
#pragma unroll
  for (int r = 0; r < 4; r++) { i1[r] = 1.f / lS[0][r]; i2[r] = lam / lS[1][r]; ssq[r] = 0.f; }
#pragma unroll
  for (int ot = 0; ot < 8; ot++)
#pragma unroll
    for (int r = 0; r < 4; r++) {
      float d = oA[0][ot][r] * i1[r] - oA[1][ot][r] * i2[r];
      oA[0][ot][r] = d;
      ssq[r] += d * d;
    }
#pragma unroll
  for (int r = 0; r < 4; r++) {
    float t = ssq[r];
    t += __shfl_xor(t, 1); t += __shfl_xor(t, 2);
    t += __shfl_xor(t, 4); t += __shfl_xor(t, 8);
    ssq[r] = ONE_M_LI / sqrtf(t * (1.f / 128.f) + 1e-5f);
  }
  const long orow = rowBase + qb * 64 + wave * 16 + quad * 4;
#pragma unroll
  for (int ot = 0; ot < 8; ot++) {
    const float gv = g[ot * 16 + l15];
#pragma unroll
    for (int r = 0; r < 4; r++)
      attnp[(orow + r) * 2048 + h * 128 + ot * 16 + l15] = f2bs(oA[0][ot][r] * ssq[r] * gv);
  }
}

// ---------- launch ----------
extern "C" void kernel_launch(void* const* d_in, const int* in_sizes, int n_in,
                              void* d_out, int out_size, void* d_ws, size_t ws_size,
                              hipStream_t stream) {
  const float* x    = (const float*)d_in[0];
  const float* cosp = (const float*)d_in[1];
  const float* sinp = (const float*)d_in[2];
  const float* Wq   = (const float*)d_in[3];
  const float* Wk   = (const float*)d_in[4];
  const float* Wv   = (const float*)d_in[5];
  const float* Wo   = (const float*)d_in[6];
  const float* lq1  = (const float*)d_in[7];
  const float* lk1  = (const float*)d_in[8];
  const float* lq2  = (const float*)d_in[9];
  const float* lk2  = (const float*)d_in[10];
  const float* g    = (const float*)d_in[11];
  float* out = (float*)d_out;

  const size_t MB = 1u << 20;
  char* ws = (char*)d_ws;
  short* xb    = (short*)(ws);            // 16 MB  x bf16 (consumed by GEMM1)
  short* Kt    = (short*)(ws);            //  8 MB  K tiled (aliases xb, written after GEMM1)
  short* Vt    = (short*)(ws + 8 * MB);   //  8 MB  V^T tiled
  short* Wqkvt = (short*)(ws + 16 * MB);  // 16 MB  [Wq|Wk|Wv]^T bf16
  short* Wot   = (short*)(ws + 32 * MB);  //  8 MB  Wo^T bf16
  short* QKVb  = (short*)(ws + 40 * MB);  // 32 MB  QKV bf16 (Q roped in place)
  short* attnp = (short*)(ws + 72 * MB);  // 16 MB  pre-Wo activations bf16

  cast_x<<<8192, 256, 0, stream>>>(x, xb, 8388608);
  dim3 tb(32, 8);
  transpose_cast<<<dim3(64, 64), tb, 0, stream>>>(Wq, Wqkvt, 2048, 0, 2048);
  transpose_cast<<<dim3(32, 64), tb, 0, stream>>>(Wk, Wqkvt, 1024, 2048, 2048);
  transpose_cast<<<dim3(32, 64), tb, 0, stream>>>(Wv, Wqkvt, 1024, 3072, 2048);
  transpose_cast<<<dim3(64, 64), tb, 0, stream>>>(Wo, Wot, 2048, 0, 2048);

  gemm_bt<1><<<dim3(32, 32), 256, 0, stream>>>(xb, Wqkvt, QKVb, 2048, 4096);
  rope_q<<<4096, 256, 0, stream>>>(QKVb, cosp, sinp);
  repack_k<<<dim3(32, 16, 2), 256, 0, stream>>>(QKVb, cosp, sinp, Kt);
  repack_v<<<dim3(32, 8, 2), 256, 0, stream>>>(QKVb, Vt);
  diffattn<<<1024, 256, 0, stream>>>(QKVb, Kt, Vt, lq1, lk1, lq2, lk2, g, attnp);
  gemm_bt<0><<<dim3(16, 32), 256, 0, stream>>>(attnp, Wot, out, 2048, 2048);
}

// Round 7
// 376.726 us; speedup vs baseline: 2.0920x; 1.0148x over previous
//
#include <hip/hip_runtime.h>
#include <math.h>

// ---------- types / helpers ----------
typedef __attribute__((ext_vector_type(4))) float f32x4;
typedef __attribute__((ext_vector_type(8))) short short8;
typedef __attribute__((ext_vector_type(4))) short short4v;

#define LAM_INIT 0.9902528750666895f
#define ONE_M_LI 0.0097471249333105f
#define QSCALE   0.18033688011112042f   // 0.125 * log2(e): S arrives pre-scaled for exp2

static __device__ __forceinline__ float bs2f(short s) {
  union { unsigned u; float f; } c;
  c.u = ((unsigned)(unsigned short)s) << 16;
  return c.f;
}
static __device__ __forceinline__ short f2bs(float f) {
  union { float f; unsigned u; } c; c.f = f;
  unsigned r = c.u + 0x7fffu + ((c.u >> 16) & 1u);   // RNE
  return (short)(r >> 16);
}
static __device__ __forceinline__ short f2bs_fast(float f) {  // round-half-up (P only)
  union { float f; unsigned u; } c; c.f = f;
  return (short)((c.u + 0x8000u) >> 16);
}
static __device__ __forceinline__ void gld16(const void* g, void* l) {
  __builtin_amdgcn_global_load_lds(
      (const __attribute__((address_space(1))) void*)g,
      (__attribute__((address_space(3))) void*)l, 16, 0, 0);
}
#if __has_builtin(__builtin_amdgcn_exp2f)
#define EXP2F(x) __builtin_amdgcn_exp2f(x)
#else
#define EXP2F(x) exp2f(x)
#endif

// ---------- elementwise cast x -> bf16 ----------
__global__ void cast_x(const float* __restrict__ x, short* __restrict__ xb, int n) {
  int i = (blockIdx.x * 256 + threadIdx.x) * 4;
  if (i < n) {
    float4 v = *(const float4*)(x + i);
    short4v o;
    o[0] = f2bs(v.x); o[1] = f2bs(v.y); o[2] = f2bs(v.z); o[3] = f2bs(v.w);
    *(short4v*)(xb + i) = o;
  }
}

// ---------- transpose-cast all four weights in one launch ----------
// z: 0=Wq(->Wqkvt+0) 1=Wk(->Wqkvt+2048) 2=Wv(->Wqkvt+3072) 3=Wo(->Wot)
__global__ void transpose_all(const float* __restrict__ Wq, const float* __restrict__ Wk,
                              const float* __restrict__ Wv, const float* __restrict__ Wo,
                              short* __restrict__ Wqkvt, short* __restrict__ Wot) {
  __shared__ float tile[32][33];
  const int z = blockIdx.z;
  const int srcCols = (z == 1 || z == 2) ? 1024 : 2048;
  if (blockIdx.x * 32 >= srcCols) return;
  const float* src = (z == 0) ? Wq : (z == 1) ? Wk : (z == 2) ? Wv : Wo;
  short* dst = (z == 3) ? Wot : Wqkvt;
  const int dstRowOff = (z == 1) ? 2048 : (z == 2) ? 3072 : 0;
  int c0 = blockIdx.x * 32, r0 = blockIdx.y * 32;
  int tx = threadIdx.x, ty = threadIdx.y;
#pragma unroll
  for (int i = 0; i < 32; i += 8)
    tile[ty + i][tx] = src[(long)(r0 + ty + i) * srcCols + c0 + tx];
  __syncthreads();
#pragma unroll
  for (int i = 0; i < 32; i += 8)
    dst[(long)(dstRowOff + c0 + ty + i) * 2048 + r0 + tx] = f2bs(tile[tx][ty + i]);
}

// ---------- m97-style GEMM with XCD-band swizzle ----------
// flat grid; bid&7 -> XCD (round-robin dispatch heuristic); each XCD owns a
// bandH-row M-band x all N so its A-band stays L2-resident.
template<int BF16OUT>
__global__ __launch_bounds__(256)
void gemm_bt(const short* __restrict__ A, const short* __restrict__ Bt,
             void* __restrict__ Cp, int K, int N,
             int bxMask, int bxShift, int bandH) {
  __shared__ __align__(16) short As[128 * 32];
  __shared__ __align__(16) short Bs[128 * 32];
  const int tid  = threadIdx.x;
  const int lane = tid & 63;
  const int wave = tid >> 6;
  const int bid  = blockIdx.x;
  const int xcd  = bid & 7;
  const int s    = bid >> 3;
  const long mBase = (long)(xcd * bandH + (s >> bxShift)) * 128;
  const long nBase = (long)(s & bxMask) * 128;
  const int wm = (wave >> 1) * 64;
  const int wn = (wave & 1) * 64;

  f32x4 acc[4][4];
#pragma unroll
  for (int i = 0; i < 4; i++)
#pragma unroll
    for (int j = 0; j < 4; j++)
#pragma unroll
      for (int r = 0; r < 4; r++) acc[i][j][r] = 0.f;

  const int r0  = tid >> 2;
  const int kp0 = (tid & 3) * 8;
  const short* a0 = A  + (mBase + r0) * K + kp0;
  const short* a1 = A  + (mBase + r0 + 64) * K + kp0;
  const short* b0 = Bt + (nBase + r0) * K + kp0;
  const short* b1 = Bt + (nBase + r0 + 64) * K + kp0;
  short* AsW = As + wave * 512;
  short* BsW = Bs + wave * 512;

  const int mr = wm + (lane & 15);
  const int nr = wn + (lane & 15);
  const int kr = (lane >> 4) * 8;

  for (int kt = 0; kt < K; kt += 32) {
    __syncthreads();
    gld16(a0 + kt, AsW);
    gld16(a1 + kt, AsW + 2048);
    gld16(b0 + kt, BsW);
    gld16(b1 + kt, BsW + 2048);
    __syncthreads();
    short8 af[4], bf[4];
#pragma unroll
    for (int mt = 0; mt < 4; mt++) af[mt] = *(const short8*)&As[(mr + mt * 16) * 32 + kr];
#pragma unroll
    for (int nt = 0; nt < 4; nt++) bf[nt] = *(const short8*)&Bs[(nr + nt * 16) * 32 + kr];
#pragma unroll
    for (int mt = 0; mt < 4; mt++)
#pragma unroll
      for (int nt = 0; nt < 4; nt++)
        acc[mt][nt] = __builtin_amdgcn_mfma_f32_16x16x32_bf16(af[mt], bf[nt], acc[mt][nt], 0, 0, 0);
  }

  const long col0 = nBase + wn + (lane & 15);
  const long row0 = mBase + wm + (lane >> 4) * 4;
#pragma unroll
  for (int mt = 0; mt < 4; mt++)
#pragma unroll
    for (int nt = 0; nt < 4; nt++)
#pragma unroll
      for (int rg = 0; rg < 4; rg++) {
        long idx = (row0 + mt * 16 + rg) * N + col0 + nt * 16;
        if (BF16OUT) ((short*)Cp)[idx] = f2bs(acc[mt][nt][rg]);
        else         ((float*)Cp)[idx] = acc[mt][nt][rg];
      }
}

// ---------- rope Q in place (scaled by 0.125*log2e), cols 0..2047 of QKVb ----------
// kept as its own kernel: fusing this into diffattn changed FMA contraction and
// tripled output absmax via the diff-softmax cancellation (round 6 post-mortem)
__global__ __launch_bounds__(256) void rope_q(short* __restrict__ QKV,
    const float* __restrict__ cosp, const float* __restrict__ sinp) {
  int idx = blockIdx.x * 256 + threadIdx.x;   // 4096 rows * 256 short8-groups
  int r = idx >> 8;
  int col = (idx & 255) * 8;
  short* p = QKV + (long)r * 4096 + col;
  short8 v = *(const short8*)p;
  int pos = r & 2047;
  int f0 = (col & 63) >> 1;
  float4 c = *(const float4*)(cosp + pos * 32 + f0);
  float4 s = *(const float4*)(sinp + pos * 32 + f0);
  float cc[4] = {c.x, c.y, c.z, c.w};
  float ss[4] = {s.x, s.y, s.z, s.w};
  short8 o;
#pragma unroll
  for (int j = 0; j < 4; j++) {
    float x0 = bs2f(v[2 * j]), x1 = bs2f(v[2 * j + 1]);
    o[2 * j]     = f2bs((x0 * cc[j] - x1 * ss[j]) * QSCALE);
    o[2 * j + 1] = f2bs((x0 * ss[j] + x1 * cc[j]) * QSCALE);
  }
  *(short8*)p = o;
}

// ---------- repack K (rope) + V (transpose) into fragment-ordered tiles, one launch ----------
// y<16: K-head y;  y>=16: V kv-head y-16
__global__ __launch_bounds__(256) void repack_kv(const short* __restrict__ QKV,
    const float* __restrict__ cosp, const float* __restrict__ sinp,
    short* __restrict__ Kt, short* __restrict__ Vt) {
  const int stile = blockIdx.x, b = blockIdx.z;
  if (blockIdx.y < 16) {
    const int h = blockIdx.y;
    short* dst = Kt + (long)((b * 16 + h) * 32 + stile) * 4096;
#pragma unroll
    for (int half = 0; half < 2; half++) {
      int o8 = threadIdx.x + half * 256;
      int r = o8 & 15, c = (o8 >> 4) & 3, ks = (o8 >> 6) & 1, gq = o8 >> 7;
      int t = stile * 64 + gq * 16 + r;
      const short* src = QKV + ((long)(b * 2048 + t)) * 4096 + 2048 + h * 64 + ks * 32 + c * 8;
      short8 v = *(const short8*)src;
      const float* cp = cosp + t * 32 + ks * 16 + c * 4;
      const float* sp = sinp + t * 32 + ks * 16 + c * 4;
      short8 o;
#pragma unroll
      for (int j = 0; j < 4; j++) {
        float x0 = bs2f(v[2 * j]), x1 = bs2f(v[2 * j + 1]);
        o[2 * j]     = f2bs(x0 * cp[j] - x1 * sp[j]);
        o[2 * j + 1] = f2bs(x0 * sp[j] + x1 * cp[j]);
      }
      *(short8*)(dst + o8 * 8) = o;
    }
  } else {
    __shared__ short Ts[64][130];
    const int tid = threadIdx.x;
    const int kv = blockIdx.y - 16;
#pragma unroll
    for (int half = 0; half < 2; half++) {
      int trow = half * 32 + (tid >> 3);
      int hwc = (tid & 7) * 16;
      const short* src = QKV + ((long)(b * 2048 + stile * 64 + trow)) * 4096 + 3072 + kv * 128 + hwc;
      *(short8*)&Ts[trow][hwc]     = *(const short8*)src;
      *(short8*)&Ts[trow][hwc + 8] = *(const short8*)(src + 8);
    }
    __syncthreads();
    short* dst = Vt + (long)((b * 8 + kv) * 32 + stile) * 8192;
#pragma unroll
    for (int k4 = 0; k4 < 4; k4++) {
      int o8 = tid + k4 * 256;
      int r = o8 & 15, c = (o8 >> 4) & 3, ks = (o8 >> 6) & 1, gq = o8 >> 7;
      int tt = ks * 32 + c * 8;
      int dv = gq * 16 + r;
      short8 o;
#pragma unroll
      for (int j = 0; j < 8; j++) o[j] = Ts[tt + j][dv];
      *(short8*)(dst + o8 * 8) = o;
    }
  }
}

// ---------- fused differential flash attention ----------
// LDS-staged fragment tiles (conflict-free b128 reads), double-buffered, 1 barrier/iter,
// XCD-local flat grid: bx&7 -> XCD, 4 (h,b) sets per XCD (2MB K/V working set < 4MB L2).
// 1024 blocks, 256 threads (4 waves x 16 q-rows). Q pre-roped by rope_q.
__global__ __launch_bounds__(256, 2)
void diffattn(const short* __restrict__ QKV, const short* __restrict__ Kt,
              const short* __restrict__ Vt,
              const float* __restrict__ lq1, const float* __restrict__ lk1,
              const float* __restrict__ lq2, const float* __restrict__ lk2,
              const float* __restrict__ g, short* __restrict__ attnp) {
  __shared__ __align__(16) short Ks[2][4096];        // 16 KB  K tile (fragment order)
  __shared__ __align__(16) short Vs[2][8192];        // 32 KB  V tile (fragment order)
  __shared__ __align__(16) short Ps[4][2][16][72];   // 18.4 KB per-wave P round-trip

  const int tid  = threadIdx.x;
  const int lane = tid & 63;
  const int wave = tid >> 6;
  const int quad = lane >> 4;
  const int l15  = lane & 15;

  // XCD-local decomposition of flat blockIdx
  const int bx   = blockIdx.x;
  const int xcd  = bx & 7;
  const int slot = bx >> 3;               // 0..127
  const int hb   = xcd * 4 + (slot & 3);  // 0..31
  const int h    = hb & 15;
  const int b    = hb >> 4;
  const int qb   = 31 - (slot >> 2);      // heavy blocks dispatched first
  const long rowBase = (long)b * 2048;

  // lambda (all lanes)
  float lam;
  {
    float v1 = lq1[lane] * lk1[lane];
    float v2 = lq2[lane] * lk2[lane];
#pragma unroll
    for (int m = 32; m >= 1; m >>= 1) { v1 += __shfl_xor(v1, m); v2 += __shfl_xor(v2, m); }
    lam = __expf(v1) - __expf(v2) + LAM_INIT;
  }

  // Q fragments (roped + scaled), heads 2h, 2h+1 (A-operand layout)
  const int tq = qb * 64 + wave * 16 + l15;
  short8 qf[2][2];
#pragma unroll
  for (int hd = 0; hd < 2; hd++)
#pragma unroll
    for (int ks = 0; ks < 2; ks++)
      qf[hd][ks] = *(const short8*)(QKV + (rowBase + tq) * 4096 + (2 * h + hd) * 64 + ks * 32 + quad * 8);

  const short* KtB = Kt + (long)((b * 16 + h) * 32) * 4096;
  const short* VtB = Vt + (long)((b * 8 + (h >> 1)) * 32) * 8192;
  short* KsB = &Ks[0][0];
  short* VsB = &Vs[0][0];

  // staging split: wave w loads K segs {2w,2w+1} + V segs {4w..4w+3}
  // global address is PER-LANE (+lane*8 shorts = 16B); LDS base wave-uniform (HW adds lane*16B)
#define STAGE(ST, BUF) do {                                                  \
    const short* kg_ = KtB + (long)(ST) * 4096 + wave * 1024 + lane * 8;     \
    const short* vg_ = VtB + (long)(ST) * 8192 + wave * 2048 + lane * 8;     \
    short* kl_ = KsB + (BUF) * 4096 + wave * 1024;                           \
    short* vl_ = VsB + (BUF) * 8192 + wave * 2048;                           \
    gld16(kg_,        kl_);                                                  \
    gld16(kg_ + 512,  kl_ + 512);                                            \
    gld16(vg_,        vl_);                                                  \
    gld16(vg_ + 512,  vl_ + 512);                                            \
    gld16(vg_ + 1024, vl_ + 1024);                                           \
    gld16(vg_ + 1536, vl_ + 1536);                                           \
  } while (0)

  float lS[2][4];
  f32x4 oA[2][8];
#pragma unroll
  for (int hd = 0; hd < 2; hd++) {
#pragma unroll
    for (int r = 0; r < 4; r++) lS[hd][r] = 0.f;
#pragma unroll
    for (int ot = 0; ot < 8; ot++)
#pragma unroll
      for (int r = 0; r < 4; r++) oA[hd][ot][r] = 0.f;
  }

  STAGE(0, 0);

  for (int st = 0; st <= qb; st++) {
    const int buf = st & 1;
    __syncthreads();                      // publishes buf (drains its gld16s)
    if (st < qb) STAGE(st + 1, buf ^ 1);  // prefetch spans the whole compute phase

    const short* Ktile = KsB + buf * 4096;
    const short* Vtile = VsB + buf * 8192;

    // S = Q K^T, both heads; C-layout (row q = quad*4+r, col s = nt*16+l15)
    f32x4 sc[2][4];
#pragma unroll
    for (int hd = 0; hd < 2; hd++)
#pragma unroll
      for (int nt = 0; nt < 4; nt++)
#pragma unroll
        for (int r = 0; r < 4; r++) sc[hd][nt][r] = 0.f;
#pragma unroll
    for (int ks = 0; ks < 2; ks++) {
      short8 kf[4];
#pragma unroll
      for (int nt = 0; nt < 4; nt++)
        kf[nt] = *(const short8*)(Ktile + (nt * 2 + ks) * 512 + lane * 8);
#pragma unroll
      for (int nt = 0; nt < 4; nt++) {
        sc[0][nt] = __builtin_amdgcn_mfma_f32_16x16x32_bf16(qf[0][ks], kf[nt], sc[0][nt], 0, 0, 0);
        sc[1][nt] = __builtin_amdgcn_mfma_f32_16x16x32_bf16(qf[1][ks], kf[nt], sc[1][nt], 0, 0, 0);
      }
    }

    // softmax terms: p = exp2(S) (S pre-scaled; bounded, no running max)
    const bool diag = (st == qb);
    const int tg = qb * 64 + wave * 16 + quad * 4;
#pragma unroll
    for (int hd = 0; hd < 2; hd++)
#pragma unroll
      for (int nt = 0; nt < 4; nt++) {
        const int sg = st * 64 + nt * 16 + l15;
#pragma unroll
        for (int r = 0; r < 4; r++) {
          float p = EXP2F(sc[hd][nt][r]);
          if (diag && (sg > tg + r)) p = 0.f;
          lS[hd][r] += p;
          Ps[wave][hd][quad * 4 + r][nt * 16 + l15] = f2bs_fast(p);
        }
      }

    // O += P V  (A = P rows, B = V^T rows; vf shared across both heads)
#pragma unroll
    for (int ks = 0; ks < 2; ks++) {
      short8 p0 = *(const short8*)&Ps[wave][0][l15][ks * 32 + quad * 8];
      short8 p1 = *(const short8*)&Ps[wave][1][l15][ks * 32 + quad * 8];
#pragma unroll
      for (int ot = 0; ot < 8; ot++) {
        short8 vf = *(const short8*)(Vtile + (ot * 2 + ks) * 512 + lane * 8);
        oA[0][ot] = __builtin_amdgcn_mfma_f32_16x16x32_bf16(p0, vf, oA[0][ot], 0, 0, 0);
        oA[1][ot] = __builtin_amdgcn_mfma_f32_16x16x32_bf16(p1, vf, oA[1][ot], 0, 0, 0);
      }
    }
  }
#undef STAGE

  // ---- epilogue: O rows q = quad*4+r, cols dv = ot*16+l15 ----
#pragma unroll
  for (int hd = 0; hd < 2; hd++)
#pragma unroll
    for (int r = 0; r < 4; r++) {
      float t = lS[hd][r];
      t += __shfl_xor(t, 1); t += __shfl_xor(t, 2);
      t += __shfl_xor(t, 4); t += __shfl_xor(t, 8);
      lS[hd][r] = t;
    }
  float i1[4], i2[4], ssq[4];
#pragma unroll
  for (int r = 0; r < 4; r++) { i1[r] = 1.f / lS[0][r]; i2[r] = lam / lS[1][r]; ssq[r] = 0.f; }
#pragma unroll
  for (int ot = 0; ot < 8; ot++)
#pragma unroll
    for (int r = 0; r < 4; r++) {
      float d = oA[0][ot][r] * i1[r] - oA[1][ot][r] * i2[r];
      oA[0][ot][r] = d;
      ssq[r] += d * d;
    }
#pragma unroll
  for (int r = 0; r < 4; r++) {
    float t = ssq[r];
    t += __shfl_xor(t, 1); t += __shfl_xor(t, 2);
    t += __shfl_xor(t, 4); t += __shfl_xor(t, 8);
    ssq[r] = ONE_M_LI / sqrtf(t * (1.f / 128.f) + 1e-5f);
  }
  const long orow = rowBase + qb * 64 + wave * 16 + quad * 4;
#pragma unroll
  for (int ot = 0; ot < 8; ot++) {
    const float gv = g[ot * 16 + l15];
#pragma unroll
    for (int r = 0; r < 4; r++)
      attnp[(orow + r) * 2048 + h * 128 + ot * 16 + l15] = f2bs(oA[0][ot][r] * ssq[r] * gv);
  }
}

// ---------- launch ----------
extern "C" void kernel_launch(void* const* d_in, const int* in_sizes, int n_in,
                              void* d_out, int out_size, void* d_ws, size_t ws_size,
                              hipStream_t stream) {
  const float* x    = (const float*)d_in[0];
  const float* cosp = (const float*)d_in[1];
  const float* sinp = (const float*)d_in[2];
  const float* Wq   = (const float*)d_in[3];
  const float* Wk   = (const float*)d_in[4];
  const float* Wv   = (const float*)d_in[5];
  const float* Wo   = (const float*)d_in[6];
  const float* lq1  = (const float*)d_in[7];
  const float* lk1  = (const float*)d_in[8];
  const float* lq2  = (const float*)d_in[9];
  const float* lk2  = (const float*)d_in[10];
  const float* g    = (const float*)d_in[11];
  float* out = (float*)d_out;

  const size_t MB = 1u << 20;
  char* ws = (char*)d_ws;
  short* xb    = (short*)(ws);            // 16 MB  x bf16 (consumed by GEMM1)
  short* Kt    = (short*)(ws);            //  8 MB  K tiled (aliases xb, written after GEMM1)
  short* Vt    = (short*)(ws + 8 * MB);   //  8 MB  V^T tiled
  short* Wqkvt = (short*)(ws + 16 * MB);  // 16 MB  [Wq|Wk|Wv]^T bf16
  short* Wot   = (short*)(ws + 32 * MB);  //  8 MB  Wo^T bf16
  short* QKVb  = (short*)(ws + 40 * MB);  // 32 MB  QKV bf16 (Q roped in place)
  short* attnp = (short*)(ws + 72 * MB);  // 16 MB  pre-Wo activations bf16

  cast_x<<<8192, 256, 0, stream>>>(x, xb, 8388608);
  transpose_all<<<dim3(64, 64, 4), dim3(32, 8), 0, stream>>>(Wq, Wk, Wv, Wo, Wqkvt, Wot);

  // G1: M=4096 N=4096 K=2048 -> 1024 blocks; per-XCD 4-row M-band x 32 n-blocks
  gemm_bt<1><<<1024, 256, 0, stream>>>(xb, Wqkvt, QKVb, 2048, 4096, 31, 5, 4);
  rope_q<<<4096, 256, 0, stream>>>(QKVb, cosp, sinp);
  repack_kv<<<dim3(32, 24, 2), 256, 0, stream>>>(QKVb, cosp, sinp, Kt, Vt);
  diffattn<<<1024, 256, 0, stream>>>(QKVb, Kt, Vt, lq1, lk1, lq2, lk2, g, attnp);
  // G2: M=4096 N=2048 K=2048 -> 512 blocks; per-XCD 4-row M-band x 16 n-blocks
  gemm_bt<0><<<512, 256, 0, stream>>>(attnp, Wot, out, 2048, 2048, 15, 4, 4);
}